// Round 2
// baseline (263.198 us; speedup 1.0000x reference)
//
#include <hip/hip_runtime.h>
#include <math.h>

typedef __attribute__((ext_vector_type(8))) _Float16 f16x8;
typedef __attribute__((ext_vector_type(4))) _Float16 f16x4;
typedef __attribute__((ext_vector_type(4))) float f32x4;

#define MFMAH(a, b, c) __builtin_amdgcn_mfma_f32_16x16x32_f16((a), (b), (c), 0, 0, 0)

// q pre-scale: 0.125 * log2(e)  (folds softmax exp->exp2 conversion into qk scale)
#define QSCALE 0.18033688011112042f
// softmax fixed offset in exp2 domain: 3 * log2(e)
#define SOFF 4.328085122666891f

// EMPIRICAL MATRIX (r7-r12 A/Bs, do not flip-flop):
//   gemm global mapping MUST keep 4-lanes-per-64B-segment
//   r12: gemm staging via global_load_lds w=16, linear LDS dest + inverse-swizzled
//        global source (rule #21). gemm_qkv left the top-5 (57.4 -> <56).
// r13 (this round): attn was LDS-pipe-bound (7.34M bank conflicts from stage
//   writes; ~47us of 56us in LDS). K/V are L2-resident per-XCD (16 same-bh
//   blocks land on one XCD; 2MB/XCD working set) -> drop K/V LDS staging,
//   load MFMA fragments directly from global (4-lanes-per-64B pattern),
//   K single-buffered, V double-buffered (named arrays, rule #20), zero
//   barriers in the inner loop. P transpose stays in wave-private LDS.

__device__ __forceinline__ void gl_lds16(const _Float16* g, _Float16* l) {
    __builtin_amdgcn_global_load_lds(
        (const __attribute__((address_space(1))) unsigned int*)g,
        (__attribute__((address_space(3))) unsigned int*)l, 16, 0, 0);
}

// ---------------- fused prep: cast x (float4), LDS-tiled weight transposes, rope ----------------
__global__ void prep_kernel(const float* __restrict__ x, const float* __restrict__ w_qkv,
                            const float* __restrict__ w_proj, _Float16* __restrict__ xb,
                            _Float16* __restrict__ wq, _Float16* __restrict__ wp,
                            float* __restrict__ ct, float* __restrict__ st,
                            float* __restrict__ xt) {
    __shared__ float tile[32][33];
    const int b = blockIdx.x, tid = threadIdx.x;
    if (b < 4096) {
        int i = (b * 256 + tid) * 4;
        float4 v = *(const float4*)&x[i];
        f16x4 h = {(_Float16)v.x, (_Float16)v.y, (_Float16)v.z, (_Float16)v.w};
        *(f16x4*)&xb[i] = h;
    } else if (b < 4096 + 3072 + 1024) {
        // weight transpose via 32x32 LDS tile: w [1024][C] -> wT [C][1024]
        int t, C;
        const float* src;
        _Float16* dst;
        if (b < 4096 + 3072) { t = b - 4096; C = 3072; src = w_qkv; dst = wq; }
        else                 { t = b - 4096 - 3072; C = 1024; src = w_proj; dst = wp; }
        const int tr = t & 31, tc = t >> 5;
        const int tx = tid & 31, ty = tid >> 5;
#pragma unroll
        for (int yy = 0; yy < 4; ++yy) {
            int r = ty + yy * 8;
            tile[r][tx] = src[(size_t)(tr * 32 + r) * C + tc * 32 + tx];
        }
        __syncthreads();
#pragma unroll
        for (int yy = 0; yy < 4; ++yy) {
            int r = ty + yy * 8;
            dst[(size_t)(tc * 32 + r) * 1024 + tr * 32 + tx] = (_Float16)tile[tx][r];
        }
    } else {
        int i = (b - 8192) * 256 + tid;
        int n = i >> 6, d = i & 63;
        int gi = n >> 6, gj = n & 63;
        int axis = d >> 5;
        int p = (d & 31) >> 1;
        float t = axis ? (float)gj : (float)gi;
        float half = axis ? 32.0f : 16.0f;
        float inv_freq = powf(10000.0f, -(float)p * (1.0f / 16.0f));
        float fr = t * inv_freq;
        float sbase = (2.0f * p + 12.8f) / 44.8f;
        float xs = powf(sbase, (t - half) * (1.0f / 64.0f));
        ct[i] = cosf(fr);
        st[i] = sinf(fr);
        xt[i] = xs;
    }
}

// ---------------- fp16 GEMM (128x128, BK=32, global_load_lds staging, XOR-swizzled source) -------
__global__ __launch_bounds__(256) void gemm_qkv_kernel(
    const _Float16* __restrict__ A_g, const _Float16* __restrict__ B_g,
    const float* __restrict__ bias, const float* __restrict__ ctab,
    const float* __restrict__ stab, const float* __restrict__ xtab,
    _Float16* __restrict__ qb, _Float16* __restrict__ kb, _Float16* __restrict__ vt) {
    __shared__ __align__(16) _Float16 Asm[4096];  // linear [row 128][slot 4][8]
    __shared__ __align__(16) _Float16 Bsm[4096];

    const int tid = threadIdx.x;
    const int lane = tid & 63, wave = tid >> 6;
    const int quad = lane >> 4, l16 = lane & 15;
    const int wm = wave >> 1, wn = wave & 1;
    const int m0 = blockIdx.x * 128, n0 = blockIdx.y * 128;

    f32x4 zero = {0.f, 0.f, 0.f, 0.f};
    f32x4 acc[4][4];
#pragma unroll
    for (int i = 0; i < 4; ++i)
#pragma unroll
        for (int j = 0; j < 4; ++j) acc[i][j] = zero;

    // chunk c -> row=c>>2, LDS slot=c&3 (linear dest). Global source quad is the
    // inverse-swizzled column chunk: g = slot ^ ((row>>1)&3). Read side applies
    // the same XOR, so fragment reads recover global quad `quad` unchanged.
    const int c1t = tid + 256;
    const int row0 = tid >> 2, s0 = tid & 3;
    const int row1 = c1t >> 2, s1 = c1t & 3;
    const int g0 = s0 ^ ((row0 >> 1) & 3);
    const int g1 = s1 ^ ((row1 >> 1) & 3);
    const _Float16* Ap0 = &A_g[(size_t)(m0 + row0) * 1024 + (g0 << 3)];
    const _Float16* Ap1 = &A_g[(size_t)(m0 + row1) * 1024 + (g1 << 3)];
    const _Float16* Bp0 = &B_g[(size_t)(n0 + row0) * 1024 + (g0 << 3)];
    const _Float16* Bp1 = &B_g[(size_t)(n0 + row1) * 1024 + (g1 << 3)];
    _Float16* La0 = &Asm[tid * 8];
    _Float16* La1 = &Asm[c1t * 8];
    _Float16* Lb0 = &Bsm[tid * 8];
    _Float16* Lb1 = &Bsm[c1t * 8];

    const int sw = (l16 >> 1) & 3;  // read-side swizzle (i-independent)

    for (int k0 = 0; k0 < 1024; k0 += 32) {
        __syncthreads();  // prior iteration's LDS reads complete
        gl_lds16(Ap0 + k0, La0);
        gl_lds16(Ap1 + k0, La1);
        gl_lds16(Bp0 + k0, Lb0);
        gl_lds16(Bp1 + k0, Lb1);
        __syncthreads();  // compiler drains vmcnt(0) here -> tile resident

        f16x8 af[4], bf[4];
#pragma unroll
        for (int i = 0; i < 4; ++i) {
            af[i] = *(const f16x8*)&Asm[(wm * 64 + i * 16 + l16) * 32 + ((quad ^ sw) << 3)];
            bf[i] = *(const f16x8*)&Bsm[(wn * 64 + i * 16 + l16) * 32 + ((quad ^ sw) << 3)];
        }
#pragma unroll
        for (int i = 0; i < 4; ++i)
#pragma unroll
            for (int j = 0; j < 4; ++j) acc[i][j] = MFMAH(af[i], bf[j], acc[i][j]);
    }

    float bj[4];
#pragma unroll
    for (int j = 0; j < 4; ++j) bj[j] = bias[n0 + wn * 64 + j * 16 + l16];

    if (n0 < 2048) {
        // q/k blocks: bias + xpos rope; q additionally scaled by 0.125*log2e
#pragma unroll
        for (int i = 0; i < 4; ++i) {
#pragma unroll
            for (int r = 0; r < 4; ++r) {
                const int row = m0 + wm * 64 + i * 16 + quad * 4 + r;
                const int b = row >> 11, nrow = row & 2047;
#pragma unroll
                for (int j = 0; j < 4; ++j) {
                    const int col = n0 + wn * 64 + j * 16 + l16;
                    float v = acc[i][j][r] + bj[j];
                    float partner = __shfl_xor(v, 1);  // rotate_half pair lives in lane^1
                    const int hh = (col >> 6) & 15;
                    const int d = col & 63;
                    const size_t o = ((size_t)(b * 16 + hh) * 2048 + nrow) * 64 + d;
                    float rh = (d & 1) ? partner : -partner;
                    const int ti = nrow * 64 + d;
                    float rv = v * ctab[ti] + rh * stab[ti];
                    float xs = xtab[ti];
                    if (col < 1024)
                        qb[o] = (_Float16)(rv * xs * QSCALE);
                    else
                        kb[o] = (_Float16)(rv / xs);
                }
            }
        }
    } else {
        // v blocks: bias only; write directly transposed vt[bh][d][n] as packed 8B rows
#pragma unroll
        for (int i = 0; i < 4; ++i) {
            const int row = m0 + wm * 64 + i * 16 + quad * 4;
            const int b = row >> 11, nrow = row & 2047;
#pragma unroll
            for (int j = 0; j < 4; ++j) {
                const int col = n0 + wn * 64 + j * 16 + l16;
                const int hh = (col >> 6) & 15;
                const int d = col & 63;
                f16x4 pv4;
#pragma unroll
                for (int r = 0; r < 4; ++r) pv4[r] = (_Float16)(acc[i][j][r] + bj[j]);
                *(f16x4*)&vt[((size_t)(b * 16 + hh) * 64 + d) * 2048 + nrow] = pv4;
            }
        }
    }
}

// ---------------- proj GEMM: 128x64 tile, global_load_lds staging, XOR-swizzled source -----------
__global__ __launch_bounds__(256) void gemm_proj_kernel(
    const _Float16* __restrict__ A_g, const _Float16* __restrict__ B_g,
    const float* __restrict__ bias, float* __restrict__ out) {
    __shared__ __align__(16) _Float16 Asm[4096];  // linear [row 128][slot 4][8]
    __shared__ __align__(16) _Float16 Bsm[2048];  // linear [row 64][slot 4][8]

    const int tid = threadIdx.x;
    const int lane = tid & 63, wave = tid >> 6;
    const int quad = lane >> 4, l16 = lane & 15;
    const int wm = wave >> 1, wn = wave & 1;
    const int m0 = blockIdx.x * 128, n0 = blockIdx.y * 64;

    f32x4 zero = {0.f, 0.f, 0.f, 0.f};
    f32x4 acc[4][2];
#pragma unroll
    for (int i = 0; i < 4; ++i)
#pragma unroll
        for (int j = 0; j < 2; ++j) acc[i][j] = zero;

    const int c1t = tid + 256;
    const int row0 = tid >> 2, s0 = tid & 3;   // rows 0..63
    const int row1 = c1t >> 2, s1 = c1t & 3;   // rows 64..127
    const int g0 = s0 ^ ((row0 >> 1) & 3);
    const int g1 = s1 ^ ((row1 >> 1) & 3);
    const _Float16* Ap0 = &A_g[(size_t)(m0 + row0) * 1024 + (g0 << 3)];
    const _Float16* Ap1 = &A_g[(size_t)(m0 + row1) * 1024 + (g1 << 3)];
    const _Float16* Bp0 = &B_g[(size_t)(n0 + row0) * 1024 + (g0 << 3)];  // rows 0..63 used
    _Float16* La0 = &Asm[tid * 8];
    _Float16* La1 = &Asm[c1t * 8];
    _Float16* Lb0 = &Bsm[tid * 8];

    const int sw = (l16 >> 1) & 3;

    for (int k0 = 0; k0 < 1024; k0 += 32) {
        __syncthreads();
        gl_lds16(Ap0 + k0, La0);
        gl_lds16(Ap1 + k0, La1);
        gl_lds16(Bp0 + k0, Lb0);
        __syncthreads();

        f16x8 af[4], bf[2];
#pragma unroll
        for (int i = 0; i < 4; ++i)
            af[i] = *(const f16x8*)&Asm[(wm * 64 + i * 16 + l16) * 32 + ((quad ^ sw) << 3)];
#pragma unroll
        for (int j = 0; j < 2; ++j)
            bf[j] = *(const f16x8*)&Bsm[(wn * 32 + j * 16 + l16) * 32 + ((quad ^ sw) << 3)];
#pragma unroll
        for (int i = 0; i < 4; ++i)
#pragma unroll
            for (int j = 0; j < 2; ++j) acc[i][j] = MFMAH(af[i], bf[j], acc[i][j]);
    }

    float bj[2];
#pragma unroll
    for (int j = 0; j < 2; ++j) bj[j] = bias[n0 + wn * 32 + j * 16 + l16];
#pragma unroll
    for (int i = 0; i < 4; ++i)
#pragma unroll
        for (int r = 0; r < 4; ++r) {
            const int row = m0 + wm * 64 + i * 16 + quad * 4 + r;
#pragma unroll
            for (int j = 0; j < 2; ++j) {
                const int col = n0 + wn * 32 + j * 16 + l16;
                out[(size_t)row * 1024 + col] = acc[i][j][r] + bj[j];
            }
        }
}

// ---------------- flash attention: direct-from-L2 K/V fragments, barrier-free, P via LDS ---------
#define PLD 72   // P LDS row stride

__global__ __launch_bounds__(256) void attn_kernel(
    const _Float16* __restrict__ qb, const _Float16* __restrict__ kb,
    const _Float16* __restrict__ vt, _Float16* __restrict__ ao) {
    __shared__ __align__(16) _Float16 Psm[4 * 32 * PLD];

    const int tid = threadIdx.x;
    const int lane = tid & 63, wave = tid >> 6;
    const int quad = lane >> 4, l16 = lane & 15;
    const int bh = blockIdx.x & 31, qt = blockIdx.x >> 5;  // same-bh blocks share an XCD/L2
    const size_t base = (size_t)bh * 2048 * 64;
    const int qrow0 = qt * 128 + wave * 32;

    f16x8 qf[2][2];
#pragma unroll
    for (int rg = 0; rg < 2; ++rg) {
        qf[rg][0] = *(const f16x8*)&qb[base + (size_t)(qrow0 + rg * 16 + l16) * 64 + quad * 8];
        qf[rg][1] = *(const f16x8*)&qb[base + (size_t)(qrow0 + rg * 16 + l16) * 64 + 32 + quad * 8];
    }

    f32x4 moff = {-SOFF, -SOFF, -SOFF, -SOFF};
    f32x4 zero = {0.f, 0.f, 0.f, 0.f};
    f32x4 o[2][4];
    float lsum[2] = {0.f, 0.f};
#pragma unroll
    for (int rg = 0; rg < 2; ++rg)
#pragma unroll
        for (int dc = 0; dc < 4; ++dc) o[rg][dc] = zero;

    // fragment-layout global pointers (4 lanes per 64B segment, 16 rows/inst)
    const _Float16* Kp = &kb[base + (size_t)l16 * 64 + quad * 8];
    const _Float16* Vp = &vt[((size_t)bh * 64 + l16) * 2048 + quad * 8];

    f16x8 kf[4][2], vfA[4][2], vfB[4][2];
    auto loadK = [&](int kt) {
#pragma unroll
        for (int kg = 0; kg < 4; ++kg) {
            const _Float16* p = Kp + (size_t)(kt + kg * 16) * 64;
            kf[kg][0] = *(const f16x8*)p;
            kf[kg][1] = *(const f16x8*)(p + 32);
        }
    };
    auto loadV = [&](f16x8 (&vf)[4][2], int kt) {
#pragma unroll
        for (int dc = 0; dc < 4; ++dc) {
            const _Float16* p = Vp + (size_t)(dc * 16) * 2048 + kt;
            vf[dc][0] = *(const f16x8*)p;
            vf[dc][1] = *(const f16x8*)(p + 32);
        }
    };

    _Float16* Pw = &Psm[wave * 32 * PLD];  // wave-private: no block barrier needed

    auto tile = [&](f16x8 (&vf)[4][2], f16x8 (&vfn)[4][2], int t) {
        f32x4 s[2][4];
#pragma unroll
        for (int kg = 0; kg < 4; ++kg) {
            s[0][kg] = MFMAH(kf[kg][0], qf[0][0], moff);
            s[0][kg] = MFMAH(kf[kg][1], qf[0][1], s[0][kg]);
            s[1][kg] = MFMAH(kf[kg][0], qf[1][0], moff);
            s[1][kg] = MFMAH(kf[kg][1], qf[1][1], s[1][kg]);
        }
        // prefetch next tile while softmax+PV run (kf dead after QK above;
        // vfn is the named other buffer -> all indices static, rule #20)
        if (t + 1 < 32) {
            loadK((t + 1) * 64);
            loadV(vfn, (t + 1) * 64);
        }
#pragma unroll
        for (int rg = 0; rg < 2; ++rg)
#pragma unroll
            for (int kg = 0; kg < 4; ++kg) {
                float p0 = __builtin_amdgcn_exp2f(s[rg][kg][0]);
                float p1 = __builtin_amdgcn_exp2f(s[rg][kg][1]);
                float p2 = __builtin_amdgcn_exp2f(s[rg][kg][2]);
                float p3 = __builtin_amdgcn_exp2f(s[rg][kg][3]);
                lsum[rg] += (p0 + p1) + (p2 + p3);
                f16x4 ph = {(_Float16)p0, (_Float16)p1, (_Float16)p2, (_Float16)p3};
                *(f16x4*)&Pw[(rg * 16 + l16) * PLD + kg * 16 + quad * 4] = ph;
            }
        f16x8 pf[2][2];
#pragma unroll
        for (int rg = 0; rg < 2; ++rg) {
            pf[rg][0] = *(const f16x8*)&Pw[(rg * 16 + l16) * PLD + quad * 8];
            pf[rg][1] = *(const f16x8*)&Pw[(rg * 16 + l16) * PLD + 32 + quad * 8];
        }
#pragma unroll
        for (int dc = 0; dc < 4; ++dc)
#pragma unroll
            for (int rg = 0; rg < 2; ++rg) {
                o[rg][dc] = MFMAH(pf[rg][0], vf[dc][0], o[rg][dc]);
                o[rg][dc] = MFMAH(pf[rg][1], vf[dc][1], o[rg][dc]);
            }
    };

    loadK(0);
    loadV(vfA, 0);
    for (int t = 0; t < 32; t += 2) {
        tile(vfA, vfB, t);
        tile(vfB, vfA, t + 1);
    }

    float linv[2][4];
#pragma unroll
    for (int rg = 0; rg < 2; ++rg) {
        float v = lsum[rg];
        v += __shfl_xor(v, 16);
        v += __shfl_xor(v, 32);
        v = 1.0f / v;
#pragma unroll
        for (int r = 0; r < 4; ++r) linv[rg][r] = __shfl(v, quad * 4 + r);
    }

    const int b = bh >> 4, hh = bh & 15;
#pragma unroll
    for (int rg = 0; rg < 2; ++rg)
#pragma unroll
        for (int dc = 0; dc < 4; ++dc)
#pragma unroll
            for (int r = 0; r < 4; ++r) {
                float v = o[rg][dc][r] * linv[rg][r];
                const int qrow = qrow0 + rg * 16 + quad * 4 + r;
                const size_t oi = ((size_t)(b * 2048 + qrow)) * 1024 + hh * 64 + dc * 16 + l16;
                ao[oi] = (_Float16)v;
            }
}

// ---------------- launcher ----------------
extern "C" void kernel_launch(void* const* d_in, const int* in_sizes, int n_in,
                              void* d_out, int out_size, void* d_ws, size_t ws_size,
                              hipStream_t stream) {
    const float* x = (const float*)d_in[0];
    const float* w_qkv = (const float*)d_in[1];
    const float* b_qkv = (const float*)d_in[2];
    const float* w_proj = (const float*)d_in[3];
    const float* b_proj = (const float*)d_in[4];
    float* out = (float*)d_out;

    char* ws = (char*)d_ws;
    size_t off = 0;
    auto take = [&](size_t bytes) { char* p = ws + off; off += bytes; return p; };
    _Float16* xbuf   = (_Float16*)take(8388608);   // x fp16 [4096][1024]
    _Float16* wqkvT  = (_Float16*)take(6291456);   // w_qkv^T [3072][1024]
    _Float16* wprojT = (_Float16*)take(2097152);   // w_proj^T [1024][1024]
    _Float16* qbuf   = (_Float16*)take(8388608);   // q (rope, *0.125*log2e)
    _Float16* kbuf   = (_Float16*)take(8388608);
    _Float16* vtbuf  = (_Float16*)take(8388608);   // v^T [bh][d][n], written by gemm_qkv
    float* ctab      = (float*)take(524288);
    float* stab      = (float*)take(524288);
    float* xtab      = (float*)take(524288);
    _Float16* ao = xbuf;  // x dead after gemm_qkv; attn output reuses it

    prep_kernel<<<8704, 256, 0, stream>>>(x, w_qkv, w_proj, xbuf, wqkvT, wprojT,
                                          ctab, stab, xtab);
    gemm_qkv_kernel<<<dim3(32, 24), 256, 0, stream>>>(xbuf, wqkvT, b_qkv,
                                                      ctab, stab, xtab, qbuf, kbuf, vtbuf);
    attn_kernel<<<512, 256, 0, stream>>>(qbuf, kbuf, vtbuf, ao);
    gemm_proj_kernel<<<dim3(32, 16), 256, 0, stream>>>(ao, wprojT, b_proj, out);
}

// Round 3
// 198.976 us; speedup vs baseline: 1.3228x; 1.3228x over previous
//
#include <hip/hip_runtime.h>
#include <math.h>

typedef __attribute__((ext_vector_type(8))) _Float16 f16x8;
typedef __attribute__((ext_vector_type(4))) _Float16 f16x4;
typedef __attribute__((ext_vector_type(4))) float f32x4;

#define MFMAH(a, b, c) __builtin_amdgcn_mfma_f32_16x16x32_f16((a), (b), (c), 0, 0, 0)

// q pre-scale: 0.125 * log2(e)  (folds softmax exp->exp2 conversion into qk scale)
#define QSCALE 0.18033688011112042f
// softmax fixed offset in exp2 domain: 3 * log2(e)
#define SOFF 4.328085122666891f

// EMPIRICAL MATRIX (r7-r13 A/Bs, do not flip-flop):
//   gemm global mapping MUST keep 4-lanes-per-64B-segment
//   r12: gemm staging via global_load_lds w=16, linear LDS dest + inverse-swizzled
//        global source (rule #21). gemm_qkv 57.4 -> ~47.
//   r13 FAILED (56->128us): direct-from-global K/V fragments are latency-bound
//        (2 waves/SIMD can't hide L2; 4x per-CU L2 traffic). K/V LDS staging REQUIRED.
// r14 (this round): attn occupancy was the deficit (2 waves/SIMD). Halve rows/wave
//   (32->16), 8-wave 512-thread blocks, same 128-row tile, same LDS layout/KLD=72
//   -> 4096 waves = 16/CU = 4/SIMD (max possible at 16-row granularity).

__device__ __forceinline__ void gl_lds16(const _Float16* g, _Float16* l) {
    __builtin_amdgcn_global_load_lds(
        (const __attribute__((address_space(1))) unsigned int*)g,
        (__attribute__((address_space(3))) unsigned int*)l, 16, 0, 0);
}

// ---------------- fused prep: cast x (float4), LDS-tiled weight transposes, rope ----------------
__global__ void prep_kernel(const float* __restrict__ x, const float* __restrict__ w_qkv,
                            const float* __restrict__ w_proj, _Float16* __restrict__ xb,
                            _Float16* __restrict__ wq, _Float16* __restrict__ wp,
                            float* __restrict__ ct, float* __restrict__ st,
                            float* __restrict__ xt) {
    __shared__ float tile[32][33];
    const int b = blockIdx.x, tid = threadIdx.x;
    if (b < 4096) {
        int i = (b * 256 + tid) * 4;
        float4 v = *(const float4*)&x[i];
        f16x4 h = {(_Float16)v.x, (_Float16)v.y, (_Float16)v.z, (_Float16)v.w};
        *(f16x4*)&xb[i] = h;
    } else if (b < 4096 + 3072 + 1024) {
        // weight transpose via 32x32 LDS tile: w [1024][C] -> wT [C][1024]
        int t, C;
        const float* src;
        _Float16* dst;
        if (b < 4096 + 3072) { t = b - 4096; C = 3072; src = w_qkv; dst = wq; }
        else                 { t = b - 4096 - 3072; C = 1024; src = w_proj; dst = wp; }
        const int tr = t & 31, tc = t >> 5;
        const int tx = tid & 31, ty = tid >> 5;
#pragma unroll
        for (int yy = 0; yy < 4; ++yy) {
            int r = ty + yy * 8;
            tile[r][tx] = src[(size_t)(tr * 32 + r) * C + tc * 32 + tx];
        }
        __syncthreads();
#pragma unroll
        for (int yy = 0; yy < 4; ++yy) {
            int r = ty + yy * 8;
            dst[(size_t)(tc * 32 + r) * 1024 + tr * 32 + tx] = (_Float16)tile[tx][r];
        }
    } else {
        int i = (b - 8192) * 256 + tid;
        int n = i >> 6, d = i & 63;
        int gi = n >> 6, gj = n & 63;
        int axis = d >> 5;
        int p = (d & 31) >> 1;
        float t = axis ? (float)gj : (float)gi;
        float half = axis ? 32.0f : 16.0f;
        float inv_freq = powf(10000.0f, -(float)p * (1.0f / 16.0f));
        float fr = t * inv_freq;
        float sbase = (2.0f * p + 12.8f) / 44.8f;
        float xs = powf(sbase, (t - half) * (1.0f / 64.0f));
        ct[i] = cosf(fr);
        st[i] = sinf(fr);
        xt[i] = xs;
    }
}

// ---------------- fp16 GEMM (128x128, BK=32, global_load_lds staging, XOR-swizzled source) -------
__global__ __launch_bounds__(256) void gemm_qkv_kernel(
    const _Float16* __restrict__ A_g, const _Float16* __restrict__ B_g,
    const float* __restrict__ bias, const float* __restrict__ ctab,
    const float* __restrict__ stab, const float* __restrict__ xtab,
    _Float16* __restrict__ qb, _Float16* __restrict__ kb, _Float16* __restrict__ vt) {
    __shared__ __align__(16) _Float16 Asm[4096];  // linear [row 128][slot 4][8]
    __shared__ __align__(16) _Float16 Bsm[4096];

    const int tid = threadIdx.x;
    const int lane = tid & 63, wave = tid >> 6;
    const int quad = lane >> 4, l16 = lane & 15;
    const int wm = wave >> 1, wn = wave & 1;
    const int m0 = blockIdx.x * 128, n0 = blockIdx.y * 128;

    f32x4 zero = {0.f, 0.f, 0.f, 0.f};
    f32x4 acc[4][4];
#pragma unroll
    for (int i = 0; i < 4; ++i)
#pragma unroll
        for (int j = 0; j < 4; ++j) acc[i][j] = zero;

    // chunk c -> row=c>>2, LDS slot=c&3 (linear dest). Global source quad is the
    // inverse-swizzled column chunk: g = slot ^ ((row>>1)&3). Read side applies
    // the same XOR, so fragment reads recover global quad `quad` unchanged.
    const int c1t = tid + 256;
    const int row0 = tid >> 2, s0 = tid & 3;
    const int row1 = c1t >> 2, s1 = c1t & 3;
    const int g0 = s0 ^ ((row0 >> 1) & 3);
    const int g1 = s1 ^ ((row1 >> 1) & 3);
    const _Float16* Ap0 = &A_g[(size_t)(m0 + row0) * 1024 + (g0 << 3)];
    const _Float16* Ap1 = &A_g[(size_t)(m0 + row1) * 1024 + (g1 << 3)];
    const _Float16* Bp0 = &B_g[(size_t)(n0 + row0) * 1024 + (g0 << 3)];
    const _Float16* Bp1 = &B_g[(size_t)(n0 + row1) * 1024 + (g1 << 3)];
    _Float16* La0 = &Asm[tid * 8];
    _Float16* La1 = &Asm[c1t * 8];
    _Float16* Lb0 = &Bsm[tid * 8];
    _Float16* Lb1 = &Bsm[c1t * 8];

    const int sw = (l16 >> 1) & 3;  // read-side swizzle (i-independent)

    for (int k0 = 0; k0 < 1024; k0 += 32) {
        __syncthreads();  // prior iteration's LDS reads complete
        gl_lds16(Ap0 + k0, La0);
        gl_lds16(Ap1 + k0, La1);
        gl_lds16(Bp0 + k0, Lb0);
        gl_lds16(Bp1 + k0, Lb1);
        __syncthreads();  // compiler drains vmcnt(0) here -> tile resident

        f16x8 af[4], bf[4];
#pragma unroll
        for (int i = 0; i < 4; ++i) {
            af[i] = *(const f16x8*)&Asm[(wm * 64 + i * 16 + l16) * 32 + ((quad ^ sw) << 3)];
            bf[i] = *(const f16x8*)&Bsm[(wn * 64 + i * 16 + l16) * 32 + ((quad ^ sw) << 3)];
        }
#pragma unroll
        for (int i = 0; i < 4; ++i)
#pragma unroll
            for (int j = 0; j < 4; ++j) acc[i][j] = MFMAH(af[i], bf[j], acc[i][j]);
    }

    float bj[4];
#pragma unroll
    for (int j = 0; j < 4; ++j) bj[j] = bias[n0 + wn * 64 + j * 16 + l16];

    if (n0 < 2048) {
        // q/k blocks: bias + xpos rope; q additionally scaled by 0.125*log2e
#pragma unroll
        for (int i = 0; i < 4; ++i) {
#pragma unroll
            for (int r = 0; r < 4; ++r) {
                const int row = m0 + wm * 64 + i * 16 + quad * 4 + r;
                const int b = row >> 11, nrow = row & 2047;
#pragma unroll
                for (int j = 0; j < 4; ++j) {
                    const int col = n0 + wn * 64 + j * 16 + l16;
                    float v = acc[i][j][r] + bj[j];
                    float partner = __shfl_xor(v, 1);  // rotate_half pair lives in lane^1
                    const int hh = (col >> 6) & 15;
                    const int d = col & 63;
                    const size_t o = ((size_t)(b * 16 + hh) * 2048 + nrow) * 64 + d;
                    float rh = (d & 1) ? partner : -partner;
                    const int ti = nrow * 64 + d;
                    float rv = v * ctab[ti] + rh * stab[ti];
                    float xs = xtab[ti];
                    if (col < 1024)
                        qb[o] = (_Float16)(rv * xs * QSCALE);
                    else
                        kb[o] = (_Float16)(rv / xs);
                }
            }
        }
    } else {
        // v blocks: bias only; write directly transposed vt[bh][d][n] as packed 8B rows
#pragma unroll
        for (int i = 0; i < 4; ++i) {
            const int row = m0 + wm * 64 + i * 16 + quad * 4;
            const int b = row >> 11, nrow = row & 2047;
#pragma unroll
            for (int j = 0; j < 4; ++j) {
                const int col = n0 + wn * 64 + j * 16 + l16;
                const int hh = (col >> 6) & 15;
                const int d = col & 63;
                f16x4 pv4;
#pragma unroll
                for (int r = 0; r < 4; ++r) pv4[r] = (_Float16)(acc[i][j][r] + bj[j]);
                *(f16x4*)&vt[((size_t)(b * 16 + hh) * 64 + d) * 2048 + nrow] = pv4;
            }
        }
    }
}

// ---------------- proj GEMM: 128x64 tile, global_load_lds staging, XOR-swizzled source -----------
__global__ __launch_bounds__(256) void gemm_proj_kernel(
    const _Float16* __restrict__ A_g, const _Float16* __restrict__ B_g,
    const float* __restrict__ bias, float* __restrict__ out) {
    __shared__ __align__(16) _Float16 Asm[4096];  // linear [row 128][slot 4][8]
    __shared__ __align__(16) _Float16 Bsm[2048];  // linear [row 64][slot 4][8]

    const int tid = threadIdx.x;
    const int lane = tid & 63, wave = tid >> 6;
    const int quad = lane >> 4, l16 = lane & 15;
    const int wm = wave >> 1, wn = wave & 1;
    const int m0 = blockIdx.x * 128, n0 = blockIdx.y * 64;

    f32x4 zero = {0.f, 0.f, 0.f, 0.f};
    f32x4 acc[4][2];
#pragma unroll
    for (int i = 0; i < 4; ++i)
#pragma unroll
        for (int j = 0; j < 2; ++j) acc[i][j] = zero;

    const int c1t = tid + 256;
    const int row0 = tid >> 2, s0 = tid & 3;   // rows 0..63
    const int row1 = c1t >> 2, s1 = c1t & 3;   // rows 64..127
    const int g0 = s0 ^ ((row0 >> 1) & 3);
    const int g1 = s1 ^ ((row1 >> 1) & 3);
    const _Float16* Ap0 = &A_g[(size_t)(m0 + row0) * 1024 + (g0 << 3)];
    const _Float16* Ap1 = &A_g[(size_t)(m0 + row1) * 1024 + (g1 << 3)];
    const _Float16* Bp0 = &B_g[(size_t)(n0 + row0) * 1024 + (g0 << 3)];  // rows 0..63 used
    _Float16* La0 = &Asm[tid * 8];
    _Float16* La1 = &Asm[c1t * 8];
    _Float16* Lb0 = &Bsm[tid * 8];

    const int sw = (l16 >> 1) & 3;

    for (int k0 = 0; k0 < 1024; k0 += 32) {
        __syncthreads();
        gl_lds16(Ap0 + k0, La0);
        gl_lds16(Ap1 + k0, La1);
        gl_lds16(Bp0 + k0, Lb0);
        __syncthreads();

        f16x8 af[4], bf[2];
#pragma unroll
        for (int i = 0; i < 4; ++i)
            af[i] = *(const f16x8*)&Asm[(wm * 64 + i * 16 + l16) * 32 + ((quad ^ sw) << 3)];
#pragma unroll
        for (int j = 0; j < 2; ++j)
            bf[j] = *(const f16x8*)&Bsm[(wn * 32 + j * 16 + l16) * 32 + ((quad ^ sw) << 3)];
#pragma unroll
        for (int i = 0; i < 4; ++i)
#pragma unroll
            for (int j = 0; j < 2; ++j) acc[i][j] = MFMAH(af[i], bf[j], acc[i][j]);
    }

    float bj[2];
#pragma unroll
    for (int j = 0; j < 2; ++j) bj[j] = bias[n0 + wn * 32 + j * 16 + l16];
#pragma unroll
    for (int i = 0; i < 4; ++i)
#pragma unroll
        for (int r = 0; r < 4; ++r) {
            const int row = m0 + wm * 64 + i * 16 + quad * 4 + r;
#pragma unroll
            for (int j = 0; j < 2; ++j) {
                const int col = n0 + wn * 32 + j * 16 + l16;
                out[(size_t)row * 1024 + col] = acc[i][j][r] + bj[j];
            }
        }
}

// ---------------- flash attention: 8 waves x 16 q-rows, K/V LDS dbuf, 16 waves/CU ---------------
#define KLD 72   // K/V LDS row stride (fp16): 144B rows
#define PLD 72   // P LDS row stride

__global__ __launch_bounds__(512) void attn_kernel(
    const _Float16* __restrict__ qb, const _Float16* __restrict__ kb,
    const _Float16* __restrict__ vt, _Float16* __restrict__ ao) {
    __shared__ __align__(16) _Float16 Ksm0[64 * KLD], Ksm1[64 * KLD];
    __shared__ __align__(16) _Float16 Vsm0[64 * KLD], Vsm1[64 * KLD];
    __shared__ __align__(16) _Float16 Psm[8 * 16 * PLD];

    const int tid = threadIdx.x;
    const int lane = tid & 63, wave = tid >> 6;  // 8 waves
    const int quad = lane >> 4, l16 = lane & 15;
    const int bh = blockIdx.x & 31, qt = blockIdx.x >> 5;  // same-bh blocks share an XCD/L2
    const size_t base = (size_t)bh * 2048 * 64;
    const int qrow0 = qt * 128 + wave * 16;  // 16 q-rows per wave

    f16x8 qf[2];
    qf[0] = *(const f16x8*)&qb[base + (size_t)(qrow0 + l16) * 64 + quad * 8];
    qf[1] = *(const f16x8*)&qb[base + (size_t)(qrow0 + l16) * 64 + 32 + quad * 8];

    f32x4 moff = {-SOFF, -SOFF, -SOFF, -SOFF};
    f32x4 zero = {0.f, 0.f, 0.f, 0.f};
    f32x4 o[4];
    float lsum = 0.f;
#pragma unroll
    for (int dc = 0; dc < 4; ++dc) o[dc] = zero;

    // staging: 512 threads, each stages one 16B chunk of K and of V (64 rows x 8 chunks)
    const int kr = tid >> 3, ko = (tid & 7) << 3;
    f16x8 pk, pv;
    auto gload = [&](int kt) {
        pk = *(const f16x8*)&kb[base + (size_t)(kt + kr) * 64 + ko];
        pv = *(const f16x8*)&vt[((size_t)bh * 64 + kr) * 2048 + kt + ko];
    };
    auto stage = [&](_Float16* Ks, _Float16* Vs) {
        *(f16x8*)&Ks[kr * KLD + ko] = pk;
        *(f16x8*)&Vs[kr * KLD + ko] = pv;
    };

    _Float16* Pw = &Psm[wave * 16 * PLD];  // wave-private: no block barrier needed

    auto compute = [&](const _Float16* Ks, const _Float16* Vs) {
        f32x4 s[4];
#pragma unroll
        for (int kg = 0; kg < 4; ++kg) {
            f16x8 kf0 = *(const f16x8*)&Ks[(kg * 16 + l16) * KLD + quad * 8];
            f16x8 kf1 = *(const f16x8*)&Ks[(kg * 16 + l16) * KLD + 32 + quad * 8];
            s[kg] = MFMAH(kf0, qf[0], moff);
            s[kg] = MFMAH(kf1, qf[1], s[kg]);
        }
#pragma unroll
        for (int kg = 0; kg < 4; ++kg) {
            float p0 = __builtin_amdgcn_exp2f(s[kg][0]);
            float p1 = __builtin_amdgcn_exp2f(s[kg][1]);
            float p2 = __builtin_amdgcn_exp2f(s[kg][2]);
            float p3 = __builtin_amdgcn_exp2f(s[kg][3]);
            lsum += (p0 + p1) + (p2 + p3);
            f16x4 ph = {(_Float16)p0, (_Float16)p1, (_Float16)p2, (_Float16)p3};
            *(f16x4*)&Pw[l16 * PLD + kg * 16 + quad * 4] = ph;
        }
        f16x8 pf0 = *(const f16x8*)&Pw[l16 * PLD + quad * 8];
        f16x8 pf1 = *(const f16x8*)&Pw[l16 * PLD + 32 + quad * 8];
#pragma unroll
        for (int dc = 0; dc < 4; ++dc) {
            f16x8 vf0 = *(const f16x8*)&Vs[(dc * 16 + l16) * KLD + quad * 8];
            f16x8 vf1 = *(const f16x8*)&Vs[(dc * 16 + l16) * KLD + 32 + quad * 8];
            o[dc] = MFMAH(pf0, vf0, o[dc]);
            o[dc] = MFMAH(pf1, vf1, o[dc]);
        }
    };

    gload(0);
    stage(Ksm0, Vsm0);
    gload(64);
    __syncthreads();

    for (int it = 0; it < 32; it += 2) {
        stage(Ksm1, Vsm1);                       // tile it+1
        if (it + 2 < 32) gload((it + 2) * 64);
        compute(Ksm0, Vsm0);                     // tile it
        __syncthreads();
        if (it + 2 < 32) stage(Ksm0, Vsm0);      // tile it+2
        if (it + 3 < 32) gload((it + 3) * 64);
        compute(Ksm1, Vsm1);                     // tile it+1
        __syncthreads();
    }

    float linv[4];
    {
        float v = lsum;
        v += __shfl_xor(v, 16);
        v += __shfl_xor(v, 32);
        v = 1.0f / v;
#pragma unroll
        for (int r = 0; r < 4; ++r) linv[r] = __shfl(v, quad * 4 + r);
    }

    const int b = bh >> 4, hh = bh & 15;
#pragma unroll
    for (int dc = 0; dc < 4; ++dc)
#pragma unroll
        for (int r = 0; r < 4; ++r) {
            float v = o[dc][r] * linv[r];
            const int qrow = qrow0 + quad * 4 + r;
            const size_t oi = ((size_t)(b * 2048 + qrow)) * 1024 + hh * 64 + dc * 16 + l16;
            ao[oi] = (_Float16)v;
        }
}

// ---------------- launcher ----------------
extern "C" void kernel_launch(void* const* d_in, const int* in_sizes, int n_in,
                              void* d_out, int out_size, void* d_ws, size_t ws_size,
                              hipStream_t stream) {
    const float* x = (const float*)d_in[0];
    const float* w_qkv = (const float*)d_in[1];
    const float* b_qkv = (const float*)d_in[2];
    const float* w_proj = (const float*)d_in[3];
    const float* b_proj = (const float*)d_in[4];
    float* out = (float*)d_out;

    char* ws = (char*)d_ws;
    size_t off = 0;
    auto take = [&](size_t bytes) { char* p = ws + off; off += bytes; return p; };
    _Float16* xbuf   = (_Float16*)take(8388608);   // x fp16 [4096][1024]
    _Float16* wqkvT  = (_Float16*)take(6291456);   // w_qkv^T [3072][1024]
    _Float16* wprojT = (_Float16*)take(2097152);   // w_proj^T [1024][1024]
    _Float16* qbuf   = (_Float16*)take(8388608);   // q (rope, *0.125*log2e)
    _Float16* kbuf   = (_Float16*)take(8388608);
    _Float16* vtbuf  = (_Float16*)take(8388608);   // v^T [bh][d][n], written by gemm_qkv
    float* ctab      = (float*)take(524288);
    float* stab      = (float*)take(524288);
    float* xtab      = (float*)take(524288);
    _Float16* ao = xbuf;  // x dead after gemm_qkv; attn output reuses it

    prep_kernel<<<8704, 256, 0, stream>>>(x, w_qkv, w_proj, xbuf, wqkvT, wprojT,
                                          ctab, stab, xtab);
    gemm_qkv_kernel<<<dim3(32, 24), 256, 0, stream>>>(xbuf, wqkvT, b_qkv,
                                                      ctab, stab, xtab, qbuf, kbuf, vtbuf);
    attn_kernel<<<512, 512, 0, stream>>>(qbuf, kbuf, vtbuf, ao);
    gemm_proj_kernel<<<dim3(32, 16), 256, 0, stream>>>(ao, wprojT, b_proj, out);
}

// Round 4
// 198.208 us; speedup vs baseline: 1.3279x; 1.0039x over previous
//
#include <hip/hip_runtime.h>
#include <math.h>

typedef __attribute__((ext_vector_type(8))) _Float16 f16x8;
typedef __attribute__((ext_vector_type(4))) _Float16 f16x4;
typedef __attribute__((ext_vector_type(4))) float f32x4;
typedef __attribute__((ext_vector_type(16))) float f32x16;

#define MFMAH(a, b, c) __builtin_amdgcn_mfma_f32_16x16x32_f16((a), (b), (c), 0, 0, 0)
#define MFMA32(a, b, c) __builtin_amdgcn_mfma_f32_32x32x16_f16((a), (b), (c), 0, 0, 0)

// q pre-scale: 0.125 * log2(e)  (folds softmax exp->exp2 conversion into qk scale)
#define QSCALE 0.18033688011112042f
// softmax fixed offset in exp2 domain: 3 * log2(e)
#define SOFF 4.328085122666891f

// EMPIRICAL MATRIX (r7-r14 A/Bs, do not flip-flop):
//   gemm global mapping MUST keep 4-lanes-per-64B-segment
//   r12: gemm staging via global_load_lds w=16, linear LDS dest + inverse-swizzled
//        global source (rule #21). gemm_qkv 57.4 -> ~47.
//   r13 FAILED (56->128us): direct-from-global K/V fragments are latency-bound.
//        K/V LDS staging REQUIRED.
//   r14 FAILED (56->62us): 16-row waves double K/V LDS read traffic; attn is
//        LDS-THROUGHPUT-bound. 32 rows/wave is the right amortization.
// r15 (this round): kill the P LDS round-trip (32KB/block/tile + serial chain):
//   32x32x16 MFMAs with swapped QK (D col = q) make P lane-local per q-row;
//   A-fragment hi/lo k-halves fixed with 2 shfl_xor(32) per 16-k chunk.
//   Psm deleted; staging/dbuf loop identical to r12.

__device__ __forceinline__ void gl_lds16(const _Float16* g, _Float16* l) {
    __builtin_amdgcn_global_load_lds(
        (const __attribute__((address_space(1))) unsigned int*)g,
        (__attribute__((address_space(3))) unsigned int*)l, 16, 0, 0);
}

__device__ __forceinline__ unsigned pkh(float a, float b) {
    union { _Float16 h[2]; unsigned u; } x;
    x.h[0] = (_Float16)a;  // RNE converts (keep rounding identical to r12)
    x.h[1] = (_Float16)b;
    return x.u;
}

// ---------------- fused prep: cast x (float4), LDS-tiled weight transposes, rope ----------------
__global__ void prep_kernel(const float* __restrict__ x, const float* __restrict__ w_qkv,
                            const float* __restrict__ w_proj, _Float16* __restrict__ xb,
                            _Float16* __restrict__ wq, _Float16* __restrict__ wp,
                            float* __restrict__ ct, float* __restrict__ st,
                            float* __restrict__ xt) {
    __shared__ float tile[32][33];
    const int b = blockIdx.x, tid = threadIdx.x;
    if (b < 4096) {
        int i = (b * 256 + tid) * 4;
        float4 v = *(const float4*)&x[i];
        f16x4 h = {(_Float16)v.x, (_Float16)v.y, (_Float16)v.z, (_Float16)v.w};
        *(f16x4*)&xb[i] = h;
    } else if (b < 4096 + 3072 + 1024) {
        // weight transpose via 32x32 LDS tile: w [1024][C] -> wT [C][1024]
        int t, C;
        const float* src;
        _Float16* dst;
        if (b < 4096 + 3072) { t = b - 4096; C = 3072; src = w_qkv; dst = wq; }
        else                 { t = b - 4096 - 3072; C = 1024; src = w_proj; dst = wp; }
        const int tr = t & 31, tc = t >> 5;
        const int tx = tid & 31, ty = tid >> 5;
#pragma unroll
        for (int yy = 0; yy < 4; ++yy) {
            int r = ty + yy * 8;
            tile[r][tx] = src[(size_t)(tr * 32 + r) * C + tc * 32 + tx];
        }
        __syncthreads();
#pragma unroll
        for (int yy = 0; yy < 4; ++yy) {
            int r = ty + yy * 8;
            dst[(size_t)(tc * 32 + r) * 1024 + tr * 32 + tx] = (_Float16)tile[tx][r];
        }
    } else {
        int i = (b - 8192) * 256 + tid;
        int n = i >> 6, d = i & 63;
        int gi = n >> 6, gj = n & 63;
        int axis = d >> 5;
        int p = (d & 31) >> 1;
        float t = axis ? (float)gj : (float)gi;
        float half = axis ? 32.0f : 16.0f;
        float inv_freq = powf(10000.0f, -(float)p * (1.0f / 16.0f));
        float fr = t * inv_freq;
        float sbase = (2.0f * p + 12.8f) / 44.8f;
        float xs = powf(sbase, (t - half) * (1.0f / 64.0f));
        ct[i] = cosf(fr);
        st[i] = sinf(fr);
        xt[i] = xs;
    }
}

// ---------------- fp16 GEMM (128x128, BK=32, global_load_lds staging, XOR-swizzled source) -------
__global__ __launch_bounds__(256) void gemm_qkv_kernel(
    const _Float16* __restrict__ A_g, const _Float16* __restrict__ B_g,
    const float* __restrict__ bias, const float* __restrict__ ctab,
    const float* __restrict__ stab, const float* __restrict__ xtab,
    _Float16* __restrict__ qb, _Float16* __restrict__ kb, _Float16* __restrict__ vt) {
    __shared__ __align__(16) _Float16 Asm[4096];  // linear [row 128][slot 4][8]
    __shared__ __align__(16) _Float16 Bsm[4096];

    const int tid = threadIdx.x;
    const int lane = tid & 63, wave = tid >> 6;
    const int quad = lane >> 4, l16 = lane & 15;
    const int wm = wave >> 1, wn = wave & 1;
    const int m0 = blockIdx.x * 128, n0 = blockIdx.y * 128;

    f32x4 zero = {0.f, 0.f, 0.f, 0.f};
    f32x4 acc[4][4];
#pragma unroll
    for (int i = 0; i < 4; ++i)
#pragma unroll
        for (int j = 0; j < 4; ++j) acc[i][j] = zero;

    // chunk c -> row=c>>2, LDS slot=c&3 (linear dest). Global source quad is the
    // inverse-swizzled column chunk: g = slot ^ ((row>>1)&3). Read side applies
    // the same XOR, so fragment reads recover global quad `quad` unchanged.
    const int c1t = tid + 256;
    const int row0 = tid >> 2, s0 = tid & 3;
    const int row1 = c1t >> 2, s1 = c1t & 3;
    const int g0 = s0 ^ ((row0 >> 1) & 3);
    const int g1 = s1 ^ ((row1 >> 1) & 3);
    const _Float16* Ap0 = &A_g[(size_t)(m0 + row0) * 1024 + (g0 << 3)];
    const _Float16* Ap1 = &A_g[(size_t)(m0 + row1) * 1024 + (g1 << 3)];
    const _Float16* Bp0 = &B_g[(size_t)(n0 + row0) * 1024 + (g0 << 3)];
    const _Float16* Bp1 = &B_g[(size_t)(n0 + row1) * 1024 + (g1 << 3)];
    _Float16* La0 = &Asm[tid * 8];
    _Float16* La1 = &Asm[c1t * 8];
    _Float16* Lb0 = &Bsm[tid * 8];
    _Float16* Lb1 = &Bsm[c1t * 8];

    const int sw = (l16 >> 1) & 3;  // read-side swizzle (i-independent)

    for (int k0 = 0; k0 < 1024; k0 += 32) {
        __syncthreads();  // prior iteration's LDS reads complete
        gl_lds16(Ap0 + k0, La0);
        gl_lds16(Ap1 + k0, La1);
        gl_lds16(Bp0 + k0, Lb0);
        gl_lds16(Bp1 + k0, Lb1);
        __syncthreads();  // compiler drains vmcnt(0) here -> tile resident

        f16x8 af[4], bf[4];
#pragma unroll
        for (int i = 0; i < 4; ++i) {
            af[i] = *(const f16x8*)&Asm[(wm * 64 + i * 16 + l16) * 32 + ((quad ^ sw) << 3)];
            bf[i] = *(const f16x8*)&Bsm[(wn * 64 + i * 16 + l16) * 32 + ((quad ^ sw) << 3)];
        }
#pragma unroll
        for (int i = 0; i < 4; ++i)
#pragma unroll
            for (int j = 0; j < 4; ++j) acc[i][j] = MFMAH(af[i], bf[j], acc[i][j]);
    }

    float bj[4];
#pragma unroll
    for (int j = 0; j < 4; ++j) bj[j] = bias[n0 + wn * 64 + j * 16 + l16];

    if (n0 < 2048) {
        // q/k blocks: bias + xpos rope; q additionally scaled by 0.125*log2e
#pragma unroll
        for (int i = 0; i < 4; ++i) {
#pragma unroll
            for (int r = 0; r < 4; ++r) {
                const int row = m0 + wm * 64 + i * 16 + quad * 4 + r;
                const int b = row >> 11, nrow = row & 2047;
#pragma unroll
                for (int j = 0; j < 4; ++j) {
                    const int col = n0 + wn * 64 + j * 16 + l16;
                    float v = acc[i][j][r] + bj[j];
                    float partner = __shfl_xor(v, 1);  // rotate_half pair lives in lane^1
                    const int hh = (col >> 6) & 15;
                    const int d = col & 63;
                    const size_t o = ((size_t)(b * 16 + hh) * 2048 + nrow) * 64 + d;
                    float rh = (d & 1) ? partner : -partner;
                    const int ti = nrow * 64 + d;
                    float rv = v * ctab[ti] + rh * stab[ti];
                    float xs = xtab[ti];
                    if (col < 1024)
                        qb[o] = (_Float16)(rv * xs * QSCALE);
                    else
                        kb[o] = (_Float16)(rv / xs);
                }
            }
        }
    } else {
        // v blocks: bias only; write directly transposed vt[bh][d][n] as packed 8B rows
#pragma unroll
        for (int i = 0; i < 4; ++i) {
            const int row = m0 + wm * 64 + i * 16 + quad * 4;
            const int b = row >> 11, nrow = row & 2047;
#pragma unroll
            for (int j = 0; j < 4; ++j) {
                const int col = n0 + wn * 64 + j * 16 + l16;
                const int hh = (col >> 6) & 15;
                const int d = col & 63;
                f16x4 pv4;
#pragma unroll
                for (int r = 0; r < 4; ++r) pv4[r] = (_Float16)(acc[i][j][r] + bj[j]);
                *(f16x4*)&vt[((size_t)(b * 16 + hh) * 64 + d) * 2048 + nrow] = pv4;
            }
        }
    }
}

// ---------------- proj GEMM: 128x64 tile, global_load_lds staging, XOR-swizzled source -----------
__global__ __launch_bounds__(256) void gemm_proj_kernel(
    const _Float16* __restrict__ A_g, const _Float16* __restrict__ B_g,
    const float* __restrict__ bias, float* __restrict__ out) {
    __shared__ __align__(16) _Float16 Asm[4096];  // linear [row 128][slot 4][8]
    __shared__ __align__(16) _Float16 Bsm[2048];  // linear [row 64][slot 4][8]

    const int tid = threadIdx.x;
    const int lane = tid & 63, wave = tid >> 6;
    const int quad = lane >> 4, l16 = lane & 15;
    const int wm = wave >> 1, wn = wave & 1;
    const int m0 = blockIdx.x * 128, n0 = blockIdx.y * 64;

    f32x4 zero = {0.f, 0.f, 0.f, 0.f};
    f32x4 acc[4][2];
#pragma unroll
    for (int i = 0; i < 4; ++i)
#pragma unroll
        for (int j = 0; j < 2; ++j) acc[i][j] = zero;

    const int c1t = tid + 256;
    const int row0 = tid >> 2, s0 = tid & 3;   // rows 0..63
    const int row1 = c1t >> 2, s1 = c1t & 3;   // rows 64..127
    const int g0 = s0 ^ ((row0 >> 1) & 3);
    const int g1 = s1 ^ ((row1 >> 1) & 3);
    const _Float16* Ap0 = &A_g[(size_t)(m0 + row0) * 1024 + (g0 << 3)];
    const _Float16* Ap1 = &A_g[(size_t)(m0 + row1) * 1024 + (g1 << 3)];
    const _Float16* Bp0 = &B_g[(size_t)(n0 + row0) * 1024 + (g0 << 3)];  // rows 0..63 used
    _Float16* La0 = &Asm[tid * 8];
    _Float16* La1 = &Asm[c1t * 8];
    _Float16* Lb0 = &Bsm[tid * 8];

    const int sw = (l16 >> 1) & 3;

    for (int k0 = 0; k0 < 1024; k0 += 32) {
        __syncthreads();
        gl_lds16(Ap0 + k0, La0);
        gl_lds16(Ap1 + k0, La1);
        gl_lds16(Bp0 + k0, Lb0);
        __syncthreads();

        f16x8 af[4], bf[2];
#pragma unroll
        for (int i = 0; i < 4; ++i)
            af[i] = *(const f16x8*)&Asm[(wm * 64 + i * 16 + l16) * 32 + ((quad ^ sw) << 3)];
#pragma unroll
        for (int j = 0; j < 2; ++j)
            bf[j] = *(const f16x8*)&Bsm[(wn * 32 + j * 16 + l16) * 32 + ((quad ^ sw) << 3)];
#pragma unroll
        for (int i = 0; i < 4; ++i)
#pragma unroll
            for (int j = 0; j < 2; ++j) acc[i][j] = MFMAH(af[i], bf[j], acc[i][j]);
    }

    float bj[2];
#pragma unroll
    for (int j = 0; j < 2; ++j) bj[j] = bias[n0 + wn * 32 + j * 16 + l16];
#pragma unroll
    for (int i = 0; i < 4; ++i)
#pragma unroll
        for (int r = 0; r < 4; ++r) {
            const int row = m0 + wm * 64 + i * 16 + quad * 4 + r;
#pragma unroll
            for (int j = 0; j < 2; ++j) {
                const int col = n0 + wn * 32 + j * 16 + l16;
                out[(size_t)row * 1024 + col] = acc[i][j][r] + bj[j];
            }
        }
}

// ---------------- flash attention: 32x32 swapped-QK, in-register P, K/V LDS dbuf ----------------
#define KLD 72   // K/V LDS row stride (fp16): 144B rows

__global__ __launch_bounds__(256) void attn_kernel(
    const _Float16* __restrict__ qb, const _Float16* __restrict__ kb,
    const _Float16* __restrict__ vt, _Float16* __restrict__ ao) {
    __shared__ __align__(16) _Float16 Ksm0[64 * KLD], Ksm1[64 * KLD];
    __shared__ __align__(16) _Float16 Vsm0[64 * KLD], Vsm1[64 * KLD];

    const int tid = threadIdx.x;
    const int lane = tid & 63, wave = tid >> 6;
    const int l32 = lane & 31, hi = lane >> 5, hi8 = hi << 3;
    const int bh = blockIdx.x & 31, qt = blockIdx.x >> 5;  // same-bh blocks share an XCD/L2
    const size_t base = (size_t)bh * 2048 * 64;
    const int qrow0 = qt * 128 + wave * 32;  // 32 q-rows per wave

    // Q as B-fragment of mfma(K,Q): col = q = l32, k-dim(d) = dc*16 + hi*8 + j
    f16x8 qf[4];
#pragma unroll
    for (int dc = 0; dc < 4; ++dc)
        qf[dc] = *(const f16x8*)&qb[base + (size_t)(qrow0 + l32) * 64 + dc * 16 + hi8];

    f32x16 moff16, zero16;
#pragma unroll
    for (int e = 0; e < 16; ++e) { moff16[e] = -SOFF; zero16[e] = 0.f; }
    f32x16 o0 = zero16, o1 = zero16;  // d-blocks 0..31 / 32..63
    float lsum = 0.f;

    // staging: identical to r12 (256 threads, 16B chunks, 64 rows x 8)
    const int kr0 = tid >> 3, ko0 = (tid & 7) << 3;
    const int kr1 = kr0 + 32;
    f16x8 pk0, pk1, pv0, pv1;
    auto gload = [&](int kt) {
        pk0 = *(const f16x8*)&kb[base + (size_t)(kt + kr0) * 64 + ko0];
        pk1 = *(const f16x8*)&kb[base + (size_t)(kt + kr1) * 64 + ko0];
        pv0 = *(const f16x8*)&vt[((size_t)bh * 64 + kr0) * 2048 + kt + ko0];
        pv1 = *(const f16x8*)&vt[((size_t)bh * 64 + kr1) * 2048 + kt + ko0];
    };
    auto stage = [&](_Float16* Ks, _Float16* Vs) {
        *(f16x8*)&Ks[kr0 * KLD + ko0] = pk0;
        *(f16x8*)&Ks[kr1 * KLD + ko0] = pk1;
        *(f16x8*)&Vs[kr0 * KLD + ko0] = pv0;
        *(f16x8*)&Vs[kr1 * KLD + ko0] = pv1;
    };

    auto compute = [&](const _Float16* Ks, const _Float16* Vs) {
        // QK^T: A = K[32 k][16 d], B = Q  ->  D[k rows][q cols]; lane holds
        // s[kb][r] = S[q=l32][k = kb*32 + (r&3)+8*(r>>2)+4*hi]
        f32x16 s0 = moff16, s1 = moff16;
#pragma unroll
        for (int dc = 0; dc < 4; ++dc) {
            f16x8 kf0 = *(const f16x8*)&Ks[l32 * KLD + dc * 16 + hi8];
            f16x8 kf1 = *(const f16x8*)&Ks[(32 + l32) * KLD + dc * 16 + hi8];
            s0 = MFMA32(kf0, qf[dc], s0);
            s1 = MFMA32(kf1, qf[dc], s1);
        }
        float p0[16], p1[16];
#pragma unroll
        for (int e = 0; e < 16; ++e) {
            p0[e] = __builtin_amdgcn_exp2f(s0[e]);
            lsum += p0[e];
        }
#pragma unroll
        for (int e = 0; e < 16; ++e) {
            p1[e] = __builtin_amdgcn_exp2f(s1[e]);
            lsum += p1[e];
        }
        // PV per 16-k chunk c: A = P[32 q][16 k] (row = q = l32, k = hi*8+j).
        // Own regs give half the k's; the other half lives in lane^32.
#pragma unroll
        for (int c = 0; c < 4; ++c) {
            const float* ps = (c < 2) ? p0 : p1;
            const int bo = (c & 1) * 8;
            unsigned lo0 = pkh(ps[bo + 0], ps[bo + 1]);
            unsigned lo1 = pkh(ps[bo + 2], ps[bo + 3]);
            unsigned hi0 = pkh(ps[bo + 4], ps[bo + 5]);
            unsigned hi1 = pkh(ps[bo + 6], ps[bo + 7]);
            unsigned send0 = hi ? lo0 : hi0;
            unsigned send1 = hi ? lo1 : hi1;
            unsigned r0 = (unsigned)__shfl_xor((int)send0, 32);
            unsigned r1 = (unsigned)__shfl_xor((int)send1, 32);
            union { unsigned w[4]; f16x8 v; } pf;
            pf.w[0] = hi ? r0 : lo0;
            pf.w[1] = hi ? r1 : lo1;
            pf.w[2] = hi ? hi0 : r0;
            pf.w[3] = hi ? hi1 : r1;
            f16x8 vf0 = *(const f16x8*)&Vs[l32 * KLD + c * 16 + hi8];
            f16x8 vf1 = *(const f16x8*)&Vs[(32 + l32) * KLD + c * 16 + hi8];
            o0 = MFMA32(pf.v, vf0, o0);
            o1 = MFMA32(pf.v, vf1, o1);
        }
    };

    gload(0);
    stage(Ksm0, Vsm0);
    gload(64);
    __syncthreads();

    for (int it = 0; it < 32; it += 2) {
        stage(Ksm1, Vsm1);                       // tile it+1
        if (it + 2 < 32) gload((it + 2) * 64);
        compute(Ksm0, Vsm0);                     // tile it
        __syncthreads();
        if (it + 2 < 32) stage(Ksm0, Vsm0);      // tile it+2
        if (it + 3 < 32) gload((it + 3) * 64);
        compute(Ksm1, Vsm1);                     // tile it+1
        __syncthreads();
    }

    // row-sum: lane l32 holds partial for q=l32 (its hi-half of k); xor-32 completes
    float vsum = lsum + __shfl_xor(lsum, 32);
    float vinv = 1.0f / vsum;
    float linv[16];
#pragma unroll
    for (int r = 0; r < 16; ++r)
        linv[r] = __shfl(vinv, (r & 3) + 8 * (r >> 2) + 4 * hi);

    const int b = bh >> 4, hh = bh & 15;
#pragma unroll
    for (int r = 0; r < 16; ++r) {
        const int qrow = qrow0 + (r & 3) + 8 * (r >> 2) + 4 * hi;
        const size_t oi = ((size_t)(b * 2048 + qrow)) * 1024 + hh * 64 + l32;
        ao[oi] = (_Float16)(o0[r] * linv[r]);
        ao[oi + 32] = (_Float16)(o1[r] * linv[r]);
    }
}

// ---------------- launcher ----------------
extern "C" void kernel_launch(void* const* d_in, const int* in_sizes, int n_in,
                              void* d_out, int out_size, void* d_ws, size_t ws_size,
                              hipStream_t stream) {
    const float* x = (const float*)d_in[0];
    const float* w_qkv = (const float*)d_in[1];
    const float* b_qkv = (const float*)d_in[2];
    const float* w_proj = (const float*)d_in[3];
    const float* b_proj = (const float*)d_in[4];
    float* out = (float*)d_out;

    char* ws = (char*)d_ws;
    size_t off = 0;
    auto take = [&](size_t bytes) { char* p = ws + off; off += bytes; return p; };
    _Float16* xbuf   = (_Float16*)take(8388608);   // x fp16 [4096][1024]
    _Float16* wqkvT  = (_Float16*)take(6291456);   // w_qkv^T [3072][1024]
    _Float16* wprojT = (_Float16*)take(2097152);   // w_proj^T [1024][1024]
    _Float16* qbuf   = (_Float16*)take(8388608);   // q (rope, *0.125*log2e)
    _Float16* kbuf   = (_Float16*)take(8388608);
    _Float16* vtbuf  = (_Float16*)take(8388608);   // v^T [bh][d][n], written by gemm_qkv
    float* ctab      = (float*)take(524288);
    float* stab      = (float*)take(524288);
    float* xtab      = (float*)take(524288);
    _Float16* ao = xbuf;  // x dead after gemm_qkv; attn output reuses it

    prep_kernel<<<8704, 256, 0, stream>>>(x, w_qkv, w_proj, xbuf, wqkvT, wprojT,
                                          ctab, stab, xtab);
    gemm_qkv_kernel<<<dim3(32, 24), 256, 0, stream>>>(xbuf, wqkvT, b_qkv,
                                                      ctab, stab, xtab, qbuf, kbuf, vtbuf);
    attn_kernel<<<512, 256, 0, stream>>>(qbuf, kbuf, vtbuf, ao);
    gemm_proj_kernel<<<dim3(32, 16), 256, 0, stream>>>(ao, wprojT, b_proj, out);
}

// Round 5
// 197.813 us; speedup vs baseline: 1.3305x; 1.0020x over previous
//
#include <hip/hip_runtime.h>
#include <math.h>

typedef __attribute__((ext_vector_type(8))) _Float16 f16x8;
typedef __attribute__((ext_vector_type(4))) _Float16 f16x4;
typedef __attribute__((ext_vector_type(4))) float f32x4;
typedef __attribute__((ext_vector_type(16))) float f32x16;

#define MFMAH(a, b, c) __builtin_amdgcn_mfma_f32_16x16x32_f16((a), (b), (c), 0, 0, 0)
#define MFMA32(a, b, c) __builtin_amdgcn_mfma_f32_32x32x16_f16((a), (b), (c), 0, 0, 0)

// q pre-scale: 0.125 * log2(e)  (folds softmax exp->exp2 conversion into qk scale)
#define QSCALE 0.18033688011112042f
// softmax fixed offset in exp2 domain: 3 * log2(e)
#define SOFF 4.328085122666891f

// EMPIRICAL MATRIX (r7-r15 A/Bs, do not flip-flop):
//   gemm global mapping MUST keep 4-lanes-per-64B-segment
//   r12: gemm staging via global_load_lds w=16, linear LDS dest + inverse-swizzled
//        global source (rule #21). gemm_qkv 57.4 -> ~47.
//   r13 FAILED (56->128us): direct-from-global K/V fragments are latency-bound.
//        K/V LDS staging REQUIRED.
//   r14 FAILED (56->62us): 16-row q-slices double per-wave K/V LDS reads; LDS-bound.
//        32 q-rows/wave is the right amortization.
//   r15 NEUTRAL (56->60us): 32x32 swapped-QK in-register P killed bank conflicts
//        and P round-trip, but VALU (exp2+pack/shfl) became the serial cost at
//        2 waves/SIMD -> latency-bound, no pipe saturated.
// r16 (this round): split-K across wave groups. 8-wave blocks: waves 0-3 own
//   k-tiles 0-15, waves 4-7 own k-tiles 16-31, separate dbuf K/V pipelines
//   (73.7KB LDS, still 2 blocks/CU) -> 4096 waves = 4/SIMD with UNCHANGED
//   total LDS/VALU/MFMA work. Linear combine (fixed-offset exp2, no max):
//   partner waves add o/lsum via one-time 33-stride LDS exchange.

__device__ __forceinline__ void gl_lds16(const _Float16* g, _Float16* l) {
    __builtin_amdgcn_global_load_lds(
        (const __attribute__((address_space(1))) unsigned int*)g,
        (__attribute__((address_space(3))) unsigned int*)l, 16, 0, 0);
}

__device__ __forceinline__ unsigned pkh(float a, float b) {
    union { _Float16 h[2]; unsigned u; } x;
    x.h[0] = (_Float16)a;  // RNE converts (keep rounding identical to r12)
    x.h[1] = (_Float16)b;
    return x.u;
}

// ---------------- fused prep: cast x (float4), LDS-tiled weight transposes, rope ----------------
__global__ void prep_kernel(const float* __restrict__ x, const float* __restrict__ w_qkv,
                            const float* __restrict__ w_proj, _Float16* __restrict__ xb,
                            _Float16* __restrict__ wq, _Float16* __restrict__ wp,
                            float* __restrict__ ct, float* __restrict__ st,
                            float* __restrict__ xt) {
    __shared__ float tile[32][33];
    const int b = blockIdx.x, tid = threadIdx.x;
    if (b < 4096) {
        int i = (b * 256 + tid) * 4;
        float4 v = *(const float4*)&x[i];
        f16x4 h = {(_Float16)v.x, (_Float16)v.y, (_Float16)v.z, (_Float16)v.w};
        *(f16x4*)&xb[i] = h;
    } else if (b < 4096 + 3072 + 1024) {
        // weight transpose via 32x32 LDS tile: w [1024][C] -> wT [C][1024]
        int t, C;
        const float* src;
        _Float16* dst;
        if (b < 4096 + 3072) { t = b - 4096; C = 3072; src = w_qkv; dst = wq; }
        else                 { t = b - 4096 - 3072; C = 1024; src = w_proj; dst = wp; }
        const int tr = t & 31, tc = t >> 5;
        const int tx = tid & 31, ty = tid >> 5;
#pragma unroll
        for (int yy = 0; yy < 4; ++yy) {
            int r = ty + yy * 8;
            tile[r][tx] = src[(size_t)(tr * 32 + r) * C + tc * 32 + tx];
        }
        __syncthreads();
#pragma unroll
        for (int yy = 0; yy < 4; ++yy) {
            int r = ty + yy * 8;
            dst[(size_t)(tc * 32 + r) * 1024 + tr * 32 + tx] = (_Float16)tile[tx][r];
        }
    } else {
        int i = (b - 8192) * 256 + tid;
        int n = i >> 6, d = i & 63;
        int gi = n >> 6, gj = n & 63;
        int axis = d >> 5;
        int p = (d & 31) >> 1;
        float t = axis ? (float)gj : (float)gi;
        float half = axis ? 32.0f : 16.0f;
        float inv_freq = powf(10000.0f, -(float)p * (1.0f / 16.0f));
        float fr = t * inv_freq;
        float sbase = (2.0f * p + 12.8f) / 44.8f;
        float xs = powf(sbase, (t - half) * (1.0f / 64.0f));
        ct[i] = cosf(fr);
        st[i] = sinf(fr);
        xt[i] = xs;
    }
}

// ---------------- fp16 GEMM (128x128, BK=32, global_load_lds staging, XOR-swizzled source) -------
__global__ __launch_bounds__(256) void gemm_qkv_kernel(
    const _Float16* __restrict__ A_g, const _Float16* __restrict__ B_g,
    const float* __restrict__ bias, const float* __restrict__ ctab,
    const float* __restrict__ stab, const float* __restrict__ xtab,
    _Float16* __restrict__ qb, _Float16* __restrict__ kb, _Float16* __restrict__ vt) {
    __shared__ __align__(16) _Float16 Asm[4096];  // linear [row 128][slot 4][8]
    __shared__ __align__(16) _Float16 Bsm[4096];

    const int tid = threadIdx.x;
    const int lane = tid & 63, wave = tid >> 6;
    const int quad = lane >> 4, l16 = lane & 15;
    const int wm = wave >> 1, wn = wave & 1;
    const int m0 = blockIdx.x * 128, n0 = blockIdx.y * 128;

    f32x4 zero = {0.f, 0.f, 0.f, 0.f};
    f32x4 acc[4][4];
#pragma unroll
    for (int i = 0; i < 4; ++i)
#pragma unroll
        for (int j = 0; j < 4; ++j) acc[i][j] = zero;

    // chunk c -> row=c>>2, LDS slot=c&3 (linear dest). Global source quad is the
    // inverse-swizzled column chunk: g = slot ^ ((row>>1)&3). Read side applies
    // the same XOR, so fragment reads recover global quad `quad` unchanged.
    const int c1t = tid + 256;
    const int row0 = tid >> 2, s0 = tid & 3;
    const int row1 = c1t >> 2, s1 = c1t & 3;
    const int g0 = s0 ^ ((row0 >> 1) & 3);
    const int g1 = s1 ^ ((row1 >> 1) & 3);
    const _Float16* Ap0 = &A_g[(size_t)(m0 + row0) * 1024 + (g0 << 3)];
    const _Float16* Ap1 = &A_g[(size_t)(m0 + row1) * 1024 + (g1 << 3)];
    const _Float16* Bp0 = &B_g[(size_t)(n0 + row0) * 1024 + (g0 << 3)];
    const _Float16* Bp1 = &B_g[(size_t)(n0 + row1) * 1024 + (g1 << 3)];
    _Float16* La0 = &Asm[tid * 8];
    _Float16* La1 = &Asm[c1t * 8];
    _Float16* Lb0 = &Bsm[tid * 8];
    _Float16* Lb1 = &Bsm[c1t * 8];

    const int sw = (l16 >> 1) & 3;  // read-side swizzle (i-independent)

    for (int k0 = 0; k0 < 1024; k0 += 32) {
        __syncthreads();  // prior iteration's LDS reads complete
        gl_lds16(Ap0 + k0, La0);
        gl_lds16(Ap1 + k0, La1);
        gl_lds16(Bp0 + k0, Lb0);
        gl_lds16(Bp1 + k0, Lb1);
        __syncthreads();  // compiler drains vmcnt(0) here -> tile resident

        f16x8 af[4], bf[4];
#pragma unroll
        for (int i = 0; i < 4; ++i) {
            af[i] = *(const f16x8*)&Asm[(wm * 64 + i * 16 + l16) * 32 + ((quad ^ sw) << 3)];
            bf[i] = *(const f16x8*)&Bsm[(wn * 64 + i * 16 + l16) * 32 + ((quad ^ sw) << 3)];
        }
#pragma unroll
        for (int i = 0; i < 4; ++i)
#pragma unroll
            for (int j = 0; j < 4; ++j) acc[i][j] = MFMAH(af[i], bf[j], acc[i][j]);
    }

    float bj[4];
#pragma unroll
    for (int j = 0; j < 4; ++j) bj[j] = bias[n0 + wn * 64 + j * 16 + l16];

    if (n0 < 2048) {
        // q/k blocks: bias + xpos rope; q additionally scaled by 0.125*log2e
#pragma unroll
        for (int i = 0; i < 4; ++i) {
#pragma unroll
            for (int r = 0; r < 4; ++r) {
                const int row = m0 + wm * 64 + i * 16 + quad * 4 + r;
                const int b = row >> 11, nrow = row & 2047;
#pragma unroll
                for (int j = 0; j < 4; ++j) {
                    const int col = n0 + wn * 64 + j * 16 + l16;
                    float v = acc[i][j][r] + bj[j];
                    float partner = __shfl_xor(v, 1);  // rotate_half pair lives in lane^1
                    const int hh = (col >> 6) & 15;
                    const int d = col & 63;
                    const size_t o = ((size_t)(b * 16 + hh) * 2048 + nrow) * 64 + d;
                    float rh = (d & 1) ? partner : -partner;
                    const int ti = nrow * 64 + d;
                    float rv = v * ctab[ti] + rh * stab[ti];
                    float xs = xtab[ti];
                    if (col < 1024)
                        qb[o] = (_Float16)(rv * xs * QSCALE);
                    else
                        kb[o] = (_Float16)(rv / xs);
                }
            }
        }
    } else {
        // v blocks: bias only; write directly transposed vt[bh][d][n] as packed 8B rows
#pragma unroll
        for (int i = 0; i < 4; ++i) {
            const int row = m0 + wm * 64 + i * 16 + quad * 4;
            const int b = row >> 11, nrow = row & 2047;
#pragma unroll
            for (int j = 0; j < 4; ++j) {
                const int col = n0 + wn * 64 + j * 16 + l16;
                const int hh = (col >> 6) & 15;
                const int d = col & 63;
                f16x4 pv4;
#pragma unroll
                for (int r = 0; r < 4; ++r) pv4[r] = (_Float16)(acc[i][j][r] + bj[j]);
                *(f16x4*)&vt[((size_t)(b * 16 + hh) * 64 + d) * 2048 + nrow] = pv4;
            }
        }
    }
}

// ---------------- proj GEMM: 128x64 tile, global_load_lds staging, XOR-swizzled source -----------
__global__ __launch_bounds__(256) void gemm_proj_kernel(
    const _Float16* __restrict__ A_g, const _Float16* __restrict__ B_g,
    const float* __restrict__ bias, float* __restrict__ out) {
    __shared__ __align__(16) _Float16 Asm[4096];  // linear [row 128][slot 4][8]
    __shared__ __align__(16) _Float16 Bsm[2048];  // linear [row 64][slot 4][8]

    const int tid = threadIdx.x;
    const int lane = tid & 63, wave = tid >> 6;
    const int quad = lane >> 4, l16 = lane & 15;
    const int wm = wave >> 1, wn = wave & 1;
    const int m0 = blockIdx.x * 128, n0 = blockIdx.y * 64;

    f32x4 zero = {0.f, 0.f, 0.f, 0.f};
    f32x4 acc[4][2];
#pragma unroll
    for (int i = 0; i < 4; ++i)
#pragma unroll
        for (int j = 0; j < 2; ++j) acc[i][j] = zero;

    const int c1t = tid + 256;
    const int row0 = tid >> 2, s0 = tid & 3;   // rows 0..63
    const int row1 = c1t >> 2, s1 = c1t & 3;   // rows 64..127
    const int g0 = s0 ^ ((row0 >> 1) & 3);
    const int g1 = s1 ^ ((row1 >> 1) & 3);
    const _Float16* Ap0 = &A_g[(size_t)(m0 + row0) * 1024 + (g0 << 3)];
    const _Float16* Ap1 = &A_g[(size_t)(m0 + row1) * 1024 + (g1 << 3)];
    const _Float16* Bp0 = &B_g[(size_t)(n0 + row0) * 1024 + (g0 << 3)];  // rows 0..63 used
    _Float16* La0 = &Asm[tid * 8];
    _Float16* La1 = &Asm[c1t * 8];
    _Float16* Lb0 = &Bsm[tid * 8];

    const int sw = (l16 >> 1) & 3;

    for (int k0 = 0; k0 < 1024; k0 += 32) {
        __syncthreads();
        gl_lds16(Ap0 + k0, La0);
        gl_lds16(Ap1 + k0, La1);
        gl_lds16(Bp0 + k0, Lb0);
        __syncthreads();

        f16x8 af[4], bf[2];
#pragma unroll
        for (int i = 0; i < 4; ++i)
            af[i] = *(const f16x8*)&Asm[(wm * 64 + i * 16 + l16) * 32 + ((quad ^ sw) << 3)];
#pragma unroll
        for (int j = 0; j < 2; ++j)
            bf[j] = *(const f16x8*)&Bsm[(wn * 32 + j * 16 + l16) * 32 + ((quad ^ sw) << 3)];
#pragma unroll
        for (int i = 0; i < 4; ++i)
#pragma unroll
            for (int j = 0; j < 2; ++j) acc[i][j] = MFMAH(af[i], bf[j], acc[i][j]);
    }

    float bj[2];
#pragma unroll
    for (int j = 0; j < 2; ++j) bj[j] = bias[n0 + wn * 32 + j * 16 + l16];
#pragma unroll
    for (int i = 0; i < 4; ++i)
#pragma unroll
        for (int r = 0; r < 4; ++r) {
            const int row = m0 + wm * 64 + i * 16 + quad * 4 + r;
#pragma unroll
            for (int j = 0; j < 2; ++j) {
                const int col = n0 + wn * 32 + j * 16 + l16;
                out[(size_t)row * 1024 + col] = acc[i][j][r] + bj[j];
            }
        }
}

// ---------------- flash attention: split-K wave groups, 32x32 swapped-QK, in-register P ----------
#define KLD 72   // K/V LDS row stride (fp16): 144B rows

__global__ __launch_bounds__(512) void attn_kernel(
    const _Float16* __restrict__ qb, const _Float16* __restrict__ kb,
    const _Float16* __restrict__ vt, _Float16* __restrict__ ao) {
    // 8 buffers x 64*KLD fp16 = 73728 B: K[grp][buf] then V[grp][buf]
    __shared__ __align__(16) _Float16 smem[8 * 64 * KLD];

    const int tid = threadIdx.x;
    const int lane = tid & 63, wave = tid >> 6;   // 8 waves
    const int w4 = wave & 3, wgrp = wave >> 2;    // q-slice, k-half
    const int l32 = lane & 31, hi = lane >> 5, hi8 = hi << 3;
    const int bh = blockIdx.x & 31, qt = blockIdx.x >> 5;  // same-bh blocks share an XCD/L2
    const size_t base = (size_t)bh * 2048 * 64;
    const int qrow0 = qt * 128 + w4 * 32;         // 32 q-rows per wave
    const int kbase = wgrp << 10;                 // this group's k-range start

    _Float16* K0 = &smem[(wgrp * 2 + 0) * 64 * KLD];
    _Float16* K1 = &smem[(wgrp * 2 + 1) * 64 * KLD];
    _Float16* V0 = &smem[(4 + wgrp * 2 + 0) * 64 * KLD];
    _Float16* V1 = &smem[(4 + wgrp * 2 + 1) * 64 * KLD];

    // Q as B-fragment of mfma(K,Q): col = q = l32, k-dim(d) = dc*16 + hi*8 + j
    f16x8 qf[4];
#pragma unroll
    for (int dc = 0; dc < 4; ++dc)
        qf[dc] = *(const f16x8*)&qb[base + (size_t)(qrow0 + l32) * 64 + dc * 16 + hi8];

    f32x16 moff16, zero16;
#pragma unroll
    for (int e = 0; e < 16; ++e) { moff16[e] = -SOFF; zero16[e] = 0.f; }
    f32x16 o0 = zero16, o1 = zero16;  // d-blocks 0..31 / 32..63
    float lsum = 0.f;

    // staging: each k-group's 256 threads stage its own 64x64 K and V tiles
    const int t256 = tid & 255;
    const int kr0 = t256 >> 3, ko0 = (t256 & 7) << 3;
    const int kr1 = kr0 + 32;
    f16x8 pk0, pk1, pv0, pv1;
    auto gload = [&](int kt) {
        pk0 = *(const f16x8*)&kb[base + (size_t)(kt + kr0) * 64 + ko0];
        pk1 = *(const f16x8*)&kb[base + (size_t)(kt + kr1) * 64 + ko0];
        pv0 = *(const f16x8*)&vt[((size_t)bh * 64 + kr0) * 2048 + kt + ko0];
        pv1 = *(const f16x8*)&vt[((size_t)bh * 64 + kr1) * 2048 + kt + ko0];
    };
    auto stage = [&](_Float16* Ks, _Float16* Vs) {
        *(f16x8*)&Ks[kr0 * KLD + ko0] = pk0;
        *(f16x8*)&Ks[kr1 * KLD + ko0] = pk1;
        *(f16x8*)&Vs[kr0 * KLD + ko0] = pv0;
        *(f16x8*)&Vs[kr1 * KLD + ko0] = pv1;
    };

    auto compute = [&](const _Float16* Ks, const _Float16* Vs) {
        // QK^T: A = K[32 k][16 d], B = Q  ->  D[k rows][q cols]; lane holds
        // s[kb][r] = S[q=l32][k = kb*32 + (r&3)+8*(r>>2)+4*hi]
        f32x16 s0 = moff16, s1 = moff16;
#pragma unroll
        for (int dc = 0; dc < 4; ++dc) {
            f16x8 kf0 = *(const f16x8*)&Ks[l32 * KLD + dc * 16 + hi8];
            f16x8 kf1 = *(const f16x8*)&Ks[(32 + l32) * KLD + dc * 16 + hi8];
            s0 = MFMA32(kf0, qf[dc], s0);
            s1 = MFMA32(kf1, qf[dc], s1);
        }
        float p0[16], p1[16];
#pragma unroll
        for (int e = 0; e < 16; ++e) {
            p0[e] = __builtin_amdgcn_exp2f(s0[e]);
            lsum += p0[e];
        }
#pragma unroll
        for (int e = 0; e < 16; ++e) {
            p1[e] = __builtin_amdgcn_exp2f(s1[e]);
            lsum += p1[e];
        }
        // PV per 16-k chunk c: A = P[32 q][16 k] (row = q = l32, k = hi*8+j).
        // Own regs give half the k's; the other half lives in lane^32.
#pragma unroll
        for (int c = 0; c < 4; ++c) {
            const float* ps = (c < 2) ? p0 : p1;
            const int bo = (c & 1) * 8;
            unsigned lo0 = pkh(ps[bo + 0], ps[bo + 1]);
            unsigned lo1 = pkh(ps[bo + 2], ps[bo + 3]);
            unsigned hi0 = pkh(ps[bo + 4], ps[bo + 5]);
            unsigned hi1 = pkh(ps[bo + 6], ps[bo + 7]);
            unsigned send0 = hi ? lo0 : hi0;
            unsigned send1 = hi ? lo1 : hi1;
            unsigned r0 = (unsigned)__shfl_xor((int)send0, 32);
            unsigned r1 = (unsigned)__shfl_xor((int)send1, 32);
            union { unsigned w[4]; f16x8 v; } pf;
            pf.w[0] = hi ? r0 : lo0;
            pf.w[1] = hi ? r1 : lo1;
            pf.w[2] = hi ? hi0 : r0;
            pf.w[3] = hi ? hi1 : r1;
            f16x8 vf0 = *(const f16x8*)&Vs[l32 * KLD + c * 16 + hi8];
            f16x8 vf1 = *(const f16x8*)&Vs[(32 + l32) * KLD + c * 16 + hi8];
            o0 = MFMA32(pf.v, vf0, o0);
            o1 = MFMA32(pf.v, vf1, o1);
        }
    };

    gload(kbase);
    stage(K0, V0);
    gload(kbase + 64);
    __syncthreads();

    for (int it = 0; it < 16; it += 2) {
        stage(K1, V1);                              // local tile it+1
        if (it + 2 < 16) gload(kbase + (it + 2) * 64);
        compute(K0, V0);                            // local tile it
        __syncthreads();
        if (it + 2 < 16) stage(K0, V0);             // local tile it+2
        if (it + 3 < 16) gload(kbase + (it + 3) * 64);
        compute(K1, V1);                            // local tile it+1
        __syncthreads();
    }

    // within-wave k-half reduce (lane l32 <-> lane^32 hold complementary k's)
    float vsum = lsum + __shfl_xor(lsum, 32);

    // cross-group combine: group 1 deposits partial o/lsum; group 0 adds.
    // stride 33 floats -> bank = (lane + idx) % 32, conflict-free.
    float* cb = (float*)smem;
    if (wgrp == 1) {
        float* p = &cb[(w4 * 64 + lane) * 33];
#pragma unroll
        for (int r = 0; r < 16; ++r) { p[r] = o0[r]; p[16 + r] = o1[r]; }
        p[32] = vsum;
    }
    __syncthreads();
    if (wgrp == 0) {
        const float* p = &cb[(w4 * 64 + lane) * 33];
#pragma unroll
        for (int r = 0; r < 16; ++r) { o0[r] += p[r]; o1[r] += p[16 + r]; }
        vsum += p[32];

        float vinv = 1.0f / vsum;
        float linv[16];
#pragma unroll
        for (int r = 0; r < 16; ++r)
            linv[r] = __shfl(vinv, (r & 3) + 8 * (r >> 2) + 4 * hi);

        const int b = bh >> 4, hh = bh & 15;
#pragma unroll
        for (int r = 0; r < 16; ++r) {
            const int qrow = qrow0 + (r & 3) + 8 * (r >> 2) + 4 * hi;
            const size_t oi = ((size_t)(b * 2048 + qrow)) * 1024 + hh * 64 + l32;
            ao[oi] = (_Float16)(o0[r] * linv[r]);
            ao[oi + 32] = (_Float16)(o1[r] * linv[r]);
        }
    }
}

// ---------------- launcher ----------------
extern "C" void kernel_launch(void* const* d_in, const int* in_sizes, int n_in,
                              void* d_out, int out_size, void* d_ws, size_t ws_size,
                              hipStream_t stream) {
    const float* x = (const float*)d_in[0];
    const float* w_qkv = (const float*)d_in[1];
    const float* b_qkv = (const float*)d_in[2];
    const float* w_proj = (const float*)d_in[3];
    const float* b_proj = (const float*)d_in[4];
    float* out = (float*)d_out;

    char* ws = (char*)d_ws;
    size_t off = 0;
    auto take = [&](size_t bytes) { char* p = ws + off; off += bytes; return p; };
    _Float16* xbuf   = (_Float16*)take(8388608);   // x fp16 [4096][1024]
    _Float16* wqkvT  = (_Float16*)take(6291456);   // w_qkv^T [3072][1024]
    _Float16* wprojT = (_Float16*)take(2097152);   // w_proj^T [1024][1024]
    _Float16* qbuf   = (_Float16*)take(8388608);   // q (rope, *0.125*log2e)
    _Float16* kbuf   = (_Float16*)take(8388608);
    _Float16* vtbuf  = (_Float16*)take(8388608);   // v^T [bh][d][n], written by gemm_qkv
    float* ctab      = (float*)take(524288);
    float* stab      = (float*)take(524288);
    float* xtab      = (float*)take(524288);
    _Float16* ao = xbuf;  // x dead after gemm_qkv; attn output reuses it

    prep_kernel<<<8704, 256, 0, stream>>>(x, w_qkv, w_proj, xbuf, wqkvT, wprojT,
                                          ctab, stab, xtab);
    gemm_qkv_kernel<<<dim3(32, 24), 256, 0, stream>>>(xbuf, wqkvT, b_qkv,
                                                      ctab, stab, xtab, qbuf, kbuf, vtbuf);
    attn_kernel<<<512, 512, 0, stream>>>(qbuf, kbuf, vtbuf, ao);
    gemm_proj_kernel<<<dim3(32, 16), 256, 0, stream>>>(ao, wprojT, b_proj, out);
}

// Round 6
// 195.124 us; speedup vs baseline: 1.3489x; 1.0138x over previous
//
#include <hip/hip_runtime.h>
#include <math.h>

typedef __attribute__((ext_vector_type(8))) _Float16 f16x8;
typedef __attribute__((ext_vector_type(4))) _Float16 f16x4;
typedef __attribute__((ext_vector_type(4))) float f32x4;
typedef __attribute__((ext_vector_type(16))) float f32x16;

#define MFMAH(a, b, c) __builtin_amdgcn_mfma_f32_16x16x32_f16((a), (b), (c), 0, 0, 0)
#define MFMA32(a, b, c) __builtin_amdgcn_mfma_f32_32x32x16_f16((a), (b), (c), 0, 0, 0)

// q pre-scale: 0.125 * log2(e)  (folds softmax exp->exp2 conversion into qk scale)
#define QSCALE 0.18033688011112042f
// softmax fixed offset in exp2 domain: 3 * log2(e)
#define SOFF 4.328085122666891f

// EMPIRICAL MATRIX (r7-r16 A/Bs, do not flip-flop):
//   gemm global mapping MUST keep 4-lanes-per-64B-segment
//   r12: gemm staging via global_load_lds w=16, linear LDS dest + inverse-swizzled
//        global source (rule #21). gemm_qkv 57.4 -> <53.6.
//   r13 FAILED (56->128us): direct-from-global K/V fragments are latency-bound.
//        K/V LDS staging REQUIRED.
//   r14 FAILED (56->62us): 16-row q-slices double per-wave K/V LDS reads; LDS-bound.
//        32 q-rows/wave is the right amortization.
//   r15 NEUTRAL (56->60us): 32x32 swapped-QK in-register P killed bank conflicts
//        and P round-trip; VALU/chain became the cost at 2 waves/SIMD.
//   r16 WIN (60.4->54.0): split-K wave groups (waves 0-3 k-low, 4-7 k-high,
//        own dbuf pipelines, 73.7KB LDS) -> 4/SIMD, linear combine.
// r17 (this round): kill the remaining cross-lane step in the tile chain.
//   QK out k-layout ((r&3)+8*(r>>2)+4*hi) vs PV A-frag k-layout (8*hi+j)
//   differ by SWAPPING k bits 2<->3 (involution). Permute V's seq axis at
//   GENERATION (gemm_qkv V epilogue stores col swap23(nrow)) -> PV A-frag
//   packs own regs in natural order (pf = pack(p[0..7])), V reads unchanged
//   b128, zero shuffles/selects. + T5 setprio(1) around MFMA clusters.

__device__ __forceinline__ void gl_lds16(const _Float16* g, _Float16* l) {
    __builtin_amdgcn_global_load_lds(
        (const __attribute__((address_space(1))) unsigned int*)g,
        (__attribute__((address_space(3))) unsigned int*)l, 16, 0, 0);
}

__device__ __forceinline__ unsigned pkh(float a, float b) {
    union { _Float16 h[2]; unsigned u; } x;
    x.h[0] = (_Float16)a;  // RNE converts (keep rounding identical to r12)
    x.h[1] = (_Float16)b;
    return x.u;
}

// ---------------- fused prep: cast x (float4), LDS-tiled weight transposes, rope ----------------
__global__ void prep_kernel(const float* __restrict__ x, const float* __restrict__ w_qkv,
                            const float* __restrict__ w_proj, _Float16* __restrict__ xb,
                            _Float16* __restrict__ wq, _Float16* __restrict__ wp,
                            float* __restrict__ ct, float* __restrict__ st,
                            float* __restrict__ xt) {
    __shared__ float tile[32][33];
    const int b = blockIdx.x, tid = threadIdx.x;
    if (b < 4096) {
        int i = (b * 256 + tid) * 4;
        float4 v = *(const float4*)&x[i];
        f16x4 h = {(_Float16)v.x, (_Float16)v.y, (_Float16)v.z, (_Float16)v.w};
        *(f16x4*)&xb[i] = h;
    } else if (b < 4096 + 3072 + 1024) {
        // weight transpose via 32x32 LDS tile: w [1024][C] -> wT [C][1024]
        int t, C;
        const float* src;
        _Float16* dst;
        if (b < 4096 + 3072) { t = b - 4096; C = 3072; src = w_qkv; dst = wq; }
        else                 { t = b - 4096 - 3072; C = 1024; src = w_proj; dst = wp; }
        const int tr = t & 31, tc = t >> 5;
        const int tx = tid & 31, ty = tid >> 5;
#pragma unroll
        for (int yy = 0; yy < 4; ++yy) {
            int r = ty + yy * 8;
            tile[r][tx] = src[(size_t)(tr * 32 + r) * C + tc * 32 + tx];
        }
        __syncthreads();
#pragma unroll
        for (int yy = 0; yy < 4; ++yy) {
            int r = ty + yy * 8;
            dst[(size_t)(tc * 32 + r) * 1024 + tr * 32 + tx] = (_Float16)tile[tx][r];
        }
    } else {
        int i = (b - 8192) * 256 + tid;
        int n = i >> 6, d = i & 63;
        int gi = n >> 6, gj = n & 63;
        int axis = d >> 5;
        int p = (d & 31) >> 1;
        float t = axis ? (float)gj : (float)gi;
        float half = axis ? 32.0f : 16.0f;
        float inv_freq = powf(10000.0f, -(float)p * (1.0f / 16.0f));
        float fr = t * inv_freq;
        float sbase = (2.0f * p + 12.8f) / 44.8f;
        float xs = powf(sbase, (t - half) * (1.0f / 64.0f));
        ct[i] = cosf(fr);
        st[i] = sinf(fr);
        xt[i] = xs;
    }
}

// ---------------- fp16 GEMM (128x128, BK=32, global_load_lds staging, XOR-swizzled source) -------
__global__ __launch_bounds__(256) void gemm_qkv_kernel(
    const _Float16* __restrict__ A_g, const _Float16* __restrict__ B_g,
    const float* __restrict__ bias, const float* __restrict__ ctab,
    const float* __restrict__ stab, const float* __restrict__ xtab,
    _Float16* __restrict__ qb, _Float16* __restrict__ kb, _Float16* __restrict__ vt) {
    __shared__ __align__(16) _Float16 Asm[4096];  // linear [row 128][slot 4][8]
    __shared__ __align__(16) _Float16 Bsm[4096];

    const int tid = threadIdx.x;
    const int lane = tid & 63, wave = tid >> 6;
    const int quad = lane >> 4, l16 = lane & 15;
    const int wm = wave >> 1, wn = wave & 1;
    const int m0 = blockIdx.x * 128, n0 = blockIdx.y * 128;

    f32x4 zero = {0.f, 0.f, 0.f, 0.f};
    f32x4 acc[4][4];
#pragma unroll
    for (int i = 0; i < 4; ++i)
#pragma unroll
        for (int j = 0; j < 4; ++j) acc[i][j] = zero;

    // chunk c -> row=c>>2, LDS slot=c&3 (linear dest). Global source quad is the
    // inverse-swizzled column chunk: g = slot ^ ((row>>1)&3). Read side applies
    // the same XOR, so fragment reads recover global quad `quad` unchanged.
    const int c1t = tid + 256;
    const int row0 = tid >> 2, s0 = tid & 3;
    const int row1 = c1t >> 2, s1 = c1t & 3;
    const int g0 = s0 ^ ((row0 >> 1) & 3);
    const int g1 = s1 ^ ((row1 >> 1) & 3);
    const _Float16* Ap0 = &A_g[(size_t)(m0 + row0) * 1024 + (g0 << 3)];
    const _Float16* Ap1 = &A_g[(size_t)(m0 + row1) * 1024 + (g1 << 3)];
    const _Float16* Bp0 = &B_g[(size_t)(n0 + row0) * 1024 + (g0 << 3)];
    const _Float16* Bp1 = &B_g[(size_t)(n0 + row1) * 1024 + (g1 << 3)];
    _Float16* La0 = &Asm[tid * 8];
    _Float16* La1 = &Asm[c1t * 8];
    _Float16* Lb0 = &Bsm[tid * 8];
    _Float16* Lb1 = &Bsm[c1t * 8];

    const int sw = (l16 >> 1) & 3;  // read-side swizzle (i-independent)

    for (int k0 = 0; k0 < 1024; k0 += 32) {
        __syncthreads();  // prior iteration's LDS reads complete
        gl_lds16(Ap0 + k0, La0);
        gl_lds16(Ap1 + k0, La1);
        gl_lds16(Bp0 + k0, Lb0);
        gl_lds16(Bp1 + k0, Lb1);
        __syncthreads();  // compiler drains vmcnt(0) here -> tile resident

        f16x8 af[4], bf[4];
#pragma unroll
        for (int i = 0; i < 4; ++i) {
            af[i] = *(const f16x8*)&Asm[(wm * 64 + i * 16 + l16) * 32 + ((quad ^ sw) << 3)];
            bf[i] = *(const f16x8*)&Bsm[(wn * 64 + i * 16 + l16) * 32 + ((quad ^ sw) << 3)];
        }
#pragma unroll
        for (int i = 0; i < 4; ++i)
#pragma unroll
            for (int j = 0; j < 4; ++j) acc[i][j] = MFMAH(af[i], bf[j], acc[i][j]);
    }

    float bj[4];
#pragma unroll
    for (int j = 0; j < 4; ++j) bj[j] = bias[n0 + wn * 64 + j * 16 + l16];

    if (n0 < 2048) {
        // q/k blocks: bias + xpos rope; q additionally scaled by 0.125*log2e
#pragma unroll
        for (int i = 0; i < 4; ++i) {
#pragma unroll
            for (int r = 0; r < 4; ++r) {
                const int row = m0 + wm * 64 + i * 16 + quad * 4 + r;
                const int b = row >> 11, nrow = row & 2047;
#pragma unroll
                for (int j = 0; j < 4; ++j) {
                    const int col = n0 + wn * 64 + j * 16 + l16;
                    float v = acc[i][j][r] + bj[j];
                    float partner = __shfl_xor(v, 1);  // rotate_half pair lives in lane^1
                    const int hh = (col >> 6) & 15;
                    const int d = col & 63;
                    const size_t o = ((size_t)(b * 16 + hh) * 2048 + nrow) * 64 + d;
                    float rh = (d & 1) ? partner : -partner;
                    const int ti = nrow * 64 + d;
                    float rv = v * ctab[ti] + rh * stab[ti];
                    float xs = xtab[ti];
                    if (col < 1024)
                        qb[o] = (_Float16)(rv * xs * QSCALE);
                    else
                        kb[o] = (_Float16)(rv / xs);
                }
            }
        }
    } else {
        // v blocks: bias only; write transposed vt[bh][d][n'] with n' = seq index
        // with bits 2<->3 SWAPPED (r17: pre-permutes V so attn's PV A-fragment
        // k-layout matches the QK output layout -> no cross-lane fixup in attn).
#pragma unroll
        for (int i = 0; i < 4; ++i) {
            const int row = m0 + wm * 64 + i * 16 + quad * 4;
            const int b = row >> 11, nrow = row & 2047;
            const int nrp = (nrow & ~12) | ((nrow & 4) << 1) | ((nrow & 8) >> 1);
#pragma unroll
            for (int j = 0; j < 4; ++j) {
                const int col = n0 + wn * 64 + j * 16 + l16;
                const int hh = (col >> 6) & 15;
                const int d = col & 63;
                f16x4 pv4;
#pragma unroll
                for (int r = 0; r < 4; ++r) pv4[r] = (_Float16)(acc[i][j][r] + bj[j]);
                *(f16x4*)&vt[((size_t)(b * 16 + hh) * 64 + d) * 2048 + nrp] = pv4;
            }
        }
    }
}

// ---------------- proj GEMM: 128x64 tile, global_load_lds staging, XOR-swizzled source -----------
__global__ __launch_bounds__(256) void gemm_proj_kernel(
    const _Float16* __restrict__ A_g, const _Float16* __restrict__ B_g,
    const float* __restrict__ bias, float* __restrict__ out) {
    __shared__ __align__(16) _Float16 Asm[4096];  // linear [row 128][slot 4][8]
    __shared__ __align__(16) _Float16 Bsm[2048];  // linear [row 64][slot 4][8]

    const int tid = threadIdx.x;
    const int lane = tid & 63, wave = tid >> 6;
    const int quad = lane >> 4, l16 = lane & 15;
    const int wm = wave >> 1, wn = wave & 1;
    const int m0 = blockIdx.x * 128, n0 = blockIdx.y * 64;

    f32x4 zero = {0.f, 0.f, 0.f, 0.f};
    f32x4 acc[4][2];
#pragma unroll
    for (int i = 0; i < 4; ++i)
#pragma unroll
        for (int j = 0; j < 2; ++j) acc[i][j] = zero;

    const int c1t = tid + 256;
    const int row0 = tid >> 2, s0 = tid & 3;   // rows 0..63
    const int row1 = c1t >> 2, s1 = c1t & 3;   // rows 64..127
    const int g0 = s0 ^ ((row0 >> 1) & 3);
    const int g1 = s1 ^ ((row1 >> 1) & 3);
    const _Float16* Ap0 = &A_g[(size_t)(m0 + row0) * 1024 + (g0 << 3)];
    const _Float16* Ap1 = &A_g[(size_t)(m0 + row1) * 1024 + (g1 << 3)];
    const _Float16* Bp0 = &B_g[(size_t)(n0 + row0) * 1024 + (g0 << 3)];  // rows 0..63 used
    _Float16* La0 = &Asm[tid * 8];
    _Float16* La1 = &Asm[c1t * 8];
    _Float16* Lb0 = &Bsm[tid * 8];

    const int sw = (l16 >> 1) & 3;

    for (int k0 = 0; k0 < 1024; k0 += 32) {
        __syncthreads();
        gl_lds16(Ap0 + k0, La0);
        gl_lds16(Ap1 + k0, La1);
        gl_lds16(Bp0 + k0, Lb0);
        __syncthreads();

        f16x8 af[4], bf[2];
#pragma unroll
        for (int i = 0; i < 4; ++i)
            af[i] = *(const f16x8*)&Asm[(wm * 64 + i * 16 + l16) * 32 + ((quad ^ sw) << 3)];
#pragma unroll
        for (int j = 0; j < 2; ++j)
            bf[j] = *(const f16x8*)&Bsm[(wn * 32 + j * 16 + l16) * 32 + ((quad ^ sw) << 3)];
#pragma unroll
        for (int i = 0; i < 4; ++i)
#pragma unroll
            for (int j = 0; j < 2; ++j) acc[i][j] = MFMAH(af[i], bf[j], acc[i][j]);
    }

    float bj[2];
#pragma unroll
    for (int j = 0; j < 2; ++j) bj[j] = bias[n0 + wn * 32 + j * 16 + l16];
#pragma unroll
    for (int i = 0; i < 4; ++i)
#pragma unroll
        for (int r = 0; r < 4; ++r) {
            const int row = m0 + wm * 64 + i * 16 + quad * 4 + r;
#pragma unroll
            for (int j = 0; j < 2; ++j) {
                const int col = n0 + wn * 32 + j * 16 + l16;
                out[(size_t)row * 1024 + col] = acc[i][j][r] + bj[j];
            }
        }
}

// ---------------- flash attention: split-K wave groups, 32x32 swapped-QK, in-register P ----------
#define KLD 72   // K/V LDS row stride (fp16): 144B rows

__global__ __launch_bounds__(512) void attn_kernel(
    const _Float16* __restrict__ qb, const _Float16* __restrict__ kb,
    const _Float16* __restrict__ vt, _Float16* __restrict__ ao) {
    // 8 buffers x 64*KLD fp16 = 73728 B: K[grp][buf] then V[grp][buf]
    __shared__ __align__(16) _Float16 smem[8 * 64 * KLD];

    const int tid = threadIdx.x;
    const int lane = tid & 63, wave = tid >> 6;   // 8 waves
    const int w4 = wave & 3, wgrp = wave >> 2;    // q-slice, k-half
    const int l32 = lane & 31, hi = lane >> 5, hi8 = hi << 3;
    const int bh = blockIdx.x & 31, qt = blockIdx.x >> 5;  // same-bh blocks share an XCD/L2
    const size_t base = (size_t)bh * 2048 * 64;
    const int qrow0 = qt * 128 + w4 * 32;         // 32 q-rows per wave
    const int kbase = wgrp << 10;                 // this group's k-range start

    _Float16* K0 = &smem[(wgrp * 2 + 0) * 64 * KLD];
    _Float16* K1 = &smem[(wgrp * 2 + 1) * 64 * KLD];
    _Float16* V0 = &smem[(4 + wgrp * 2 + 0) * 64 * KLD];
    _Float16* V1 = &smem[(4 + wgrp * 2 + 1) * 64 * KLD];

    // Q as B-fragment of mfma(K,Q): col = q = l32, k-dim(d) = dc*16 + hi*8 + j
    f16x8 qf[4];
#pragma unroll
    for (int dc = 0; dc < 4; ++dc)
        qf[dc] = *(const f16x8*)&qb[base + (size_t)(qrow0 + l32) * 64 + dc * 16 + hi8];

    f32x16 moff16, zero16;
#pragma unroll
    for (int e = 0; e < 16; ++e) { moff16[e] = -SOFF; zero16[e] = 0.f; }
    f32x16 o0 = zero16, o1 = zero16;  // d-blocks 0..31 / 32..63
    float lsum = 0.f;

    // staging: each k-group's 256 threads stage its own 64x64 K and V tiles
    const int t256 = tid & 255;
    const int kr0 = t256 >> 3, ko0 = (t256 & 7) << 3;
    const int kr1 = kr0 + 32;
    f16x8 pk0, pk1, pv0, pv1;
    auto gload = [&](int kt) {
        pk0 = *(const f16x8*)&kb[base + (size_t)(kt + kr0) * 64 + ko0];
        pk1 = *(const f16x8*)&kb[base + (size_t)(kt + kr1) * 64 + ko0];
        pv0 = *(const f16x8*)&vt[((size_t)bh * 64 + kr0) * 2048 + kt + ko0];
        pv1 = *(const f16x8*)&vt[((size_t)bh * 64 + kr1) * 2048 + kt + ko0];
    };
    auto stage = [&](_Float16* Ks, _Float16* Vs) {
        *(f16x8*)&Ks[kr0 * KLD + ko0] = pk0;
        *(f16x8*)&Ks[kr1 * KLD + ko0] = pk1;
        *(f16x8*)&Vs[kr0 * KLD + ko0] = pv0;
        *(f16x8*)&Vs[kr1 * KLD + ko0] = pv1;
    };

    auto compute = [&](const _Float16* Ks, const _Float16* Vs) {
        // QK^T: A = K[32 k][16 d], B = Q  ->  D[k rows][q cols]; lane holds
        // s[kb][r] = S[q=l32][k = kb*32 + (r&3)+8*(r>>2)+4*hi]
        f32x16 s0 = moff16, s1 = moff16;
        __builtin_amdgcn_s_setprio(1);
#pragma unroll
        for (int dc = 0; dc < 4; ++dc) {
            f16x8 kf0 = *(const f16x8*)&Ks[l32 * KLD + dc * 16 + hi8];
            f16x8 kf1 = *(const f16x8*)&Ks[(32 + l32) * KLD + dc * 16 + hi8];
            s0 = MFMA32(kf0, qf[dc], s0);
            s1 = MFMA32(kf1, qf[dc], s1);
        }
        __builtin_amdgcn_s_setprio(0);
        float p0[16], p1[16];
#pragma unroll
        for (int e = 0; e < 16; ++e) {
            p0[e] = __builtin_amdgcn_exp2f(s0[e]);
            lsum += p0[e];
        }
#pragma unroll
        for (int e = 0; e < 16; ++e) {
            p1[e] = __builtin_amdgcn_exp2f(s1[e]);
            lsum += p1[e];
        }
        // PV per 16-k chunk c. V's seq axis was stored with k bits 2<->3 swapped,
        // which exactly matches the QK output reg order: A-frag slot j = own p[j]
        // of the chunk's 8-block. No cross-lane traffic.
        __builtin_amdgcn_s_setprio(1);
#pragma unroll
        for (int c = 0; c < 4; ++c) {
            const float* ps = (c < 2) ? p0 : p1;
            const int bo = (c & 1) * 8;
            union { unsigned w[4]; f16x8 v; } pf;
            pf.w[0] = pkh(ps[bo + 0], ps[bo + 1]);
            pf.w[1] = pkh(ps[bo + 2], ps[bo + 3]);
            pf.w[2] = pkh(ps[bo + 4], ps[bo + 5]);
            pf.w[3] = pkh(ps[bo + 6], ps[bo + 7]);
            f16x8 vf0 = *(const f16x8*)&Vs[l32 * KLD + c * 16 + hi8];
            f16x8 vf1 = *(const f16x8*)&Vs[(32 + l32) * KLD + c * 16 + hi8];
            o0 = MFMA32(pf.v, vf0, o0);
            o1 = MFMA32(pf.v, vf1, o1);
        }
        __builtin_amdgcn_s_setprio(0);
    };

    gload(kbase);
    stage(K0, V0);
    gload(kbase + 64);
    __syncthreads();

    for (int it = 0; it < 16; it += 2) {
        stage(K1, V1);                              // local tile it+1
        if (it + 2 < 16) gload(kbase + (it + 2) * 64);
        compute(K0, V0);                            // local tile it
        __syncthreads();
        if (it + 2 < 16) stage(K0, V0);             // local tile it+2
        if (it + 3 < 16) gload(kbase + (it + 3) * 64);
        compute(K1, V1);                            // local tile it+1
        __syncthreads();
    }

    // within-wave k-half reduce (lane l32 <-> lane^32 hold complementary k's)
    float vsum = lsum + __shfl_xor(lsum, 32);

    // cross-group combine: group 1 deposits partial o/lsum; group 0 adds.
    // stride 33 floats -> bank = (lane + idx) % 32, conflict-free.
    float* cb = (float*)smem;
    if (wgrp == 1) {
        float* p = &cb[(w4 * 64 + lane) * 33];
#pragma unroll
        for (int r = 0; r < 16; ++r) { p[r] = o0[r]; p[16 + r] = o1[r]; }
        p[32] = vsum;
    }
    __syncthreads();
    if (wgrp == 0) {
        const float* p = &cb[(w4 * 64 + lane) * 33];
#pragma unroll
        for (int r = 0; r < 16; ++r) { o0[r] += p[r]; o1[r] += p[16 + r]; }
        vsum += p[32];

        float vinv = 1.0f / vsum;
        float linv[16];
#pragma unroll
        for (int r = 0; r < 16; ++r)
            linv[r] = __shfl(vinv, (r & 3) + 8 * (r >> 2) + 4 * hi);

        const int b = bh >> 4, hh = bh & 15;
#pragma unroll
        for (int r = 0; r < 16; ++r) {
            const int qrow = qrow0 + (r & 3) + 8 * (r >> 2) + 4 * hi;
            const size_t oi = ((size_t)(b * 2048 + qrow)) * 1024 + hh * 64 + l32;
            ao[oi] = (_Float16)(o0[r] * linv[r]);
            ao[oi + 32] = (_Float16)(o1[r] * linv[r]);
        }
    }
}

// ---------------- launcher ----------------
extern "C" void kernel_launch(void* const* d_in, const int* in_sizes, int n_in,
                              void* d_out, int out_size, void* d_ws, size_t ws_size,
                              hipStream_t stream) {
    const float* x = (const float*)d_in[0];
    const float* w_qkv = (const float*)d_in[1];
    const float* b_qkv = (const float*)d_in[2];
    const float* w_proj = (const float*)d_in[3];
    const float* b_proj = (const float*)d_in[4];
    float* out = (float*)d_out;

    char* ws = (char*)d_ws;
    size_t off = 0;
    auto take = [&](size_t bytes) { char* p = ws + off; off += bytes; return p; };
    _Float16* xbuf   = (_Float16*)take(8388608);   // x fp16 [4096][1024]
    _Float16* wqkvT  = (_Float16*)take(6291456);   // w_qkv^T [3072][1024]
    _Float16* wprojT = (_Float16*)take(2097152);   // w_proj^T [1024][1024]
    _Float16* qbuf   = (_Float16*)take(8388608);   // q (rope, *0.125*log2e)
    _Float16* kbuf   = (_Float16*)take(8388608);
    _Float16* vtbuf  = (_Float16*)take(8388608);   // v^T [bh][d][n bit2<->3], by gemm_qkv
    float* ctab      = (float*)take(524288);
    float* stab      = (float*)take(524288);
    float* xtab      = (float*)take(524288);
    _Float16* ao = xbuf;  // x dead after gemm_qkv; attn output reuses it

    prep_kernel<<<8704, 256, 0, stream>>>(x, w_qkv, w_proj, xbuf, wqkvT, wprojT,
                                          ctab, stab, xtab);
    gemm_qkv_kernel<<<dim3(32, 24), 256, 0, stream>>>(xbuf, wqkvT, b_qkv,
                                                      ctab, stab, xtab, qbuf, kbuf, vtbuf);
    attn_kernel<<<512, 512, 0, stream>>>(qbuf, kbuf, vtbuf, ao);
    gemm_proj_kernel<<<dim3(32, 16), 256, 0, stream>>>(ao, wprojT, b_proj, out);
}